// Round 16
// baseline (773.064 us; speedup 1.0000x reference)
//
#include <hip/hip_runtime.h>
#include <hip/hip_bf16.h>
#include <hip/hip_fp16.h>

// GGM encode, decomposed (inputs fp32; internal fp16 MFMA, fp32 accum; output fp32):
//   agg[v] = deg(v)*(U1 h_v + c_k) + U2*S_h[v] + U3*S_e[v]
//   GRU: gi = agg@Wih^T + bih, gh = h@Whh^T + bhh, fused elementwise in fp32.
// R15->R16: pin B-fragments in registers with opaque asm keep-alive. R15's VGPR=84
// proved the compiler REMATERIALIZED the loop-invariant B loads per row-tile
// (24 dependent uncoalesced loads/tile -> latency chain, 97us). asm volatile
// ("":"+v"(frag)) makes the values asm-defined -> remat impossible. Barrier-free
// wave-per-nb structure and h16 ping-pong kept from R15.

#define D_NODE 128
#define D_EDGE 64
#define D_IN   322
#define GRU3   384
#define MROWS  128      // rows per block for agg/gru (8 tiles of 16)

typedef _Float16 f16x8 __attribute__((ext_vector_type(8)));
typedef _Float16 f16x4 __attribute__((ext_vector_type(4)));
typedef _Float16 f16x2 __attribute__((ext_vector_type(2)));
typedef float    f32x4 __attribute__((ext_vector_type(4)));
typedef unsigned short u16x8 __attribute__((ext_vector_type(8)));

__device__ __forceinline__ f16x8 as_f16x8(u16x8 v) { return __builtin_bit_cast(f16x8, v); }
__device__ __forceinline__ float sigm_(float x) { return 1.f / (1.f + __expf(-x)); }
__device__ __forceinline__ float tanh_(float x) { return 1.f - 2.f / (__expf(2.f * x) + 1.f); }
// Opaque register pin: value becomes asm-defined; compiler cannot re-load it.
#define KEEPV(x) asm volatile("" : "+v"(x))

// ---------------- CSR build ----------------
__global__ void hist_k(const int* __restrict__ dst, int* __restrict__ cnt, int E) {
    int t = blockIdx.x * 256 + threadIdx.x;
    if (t < E) atomicAdd(&cnt[dst[t]], 1);
}

__global__ __launch_bounds__(256) void scan1_k(const int* __restrict__ cnt, int* __restrict__ row_ptr,
                                               int* __restrict__ blk_sums, int N) {
    __shared__ int s[256];
    const int t = threadIdx.x;
    const int base = blockIdx.x * 1024 + t * 4;
    int v0 = (base + 0 < N) ? cnt[base + 0] : 0;
    int v1 = (base + 1 < N) ? cnt[base + 1] : 0;
    int v2 = (base + 2 < N) ? cnt[base + 2] : 0;
    int v3 = (base + 3 < N) ? cnt[base + 3] : 0;
    const int tot = v0 + v1 + v2 + v3;
    s[t] = tot;
    __syncthreads();
    for (int off = 1; off < 256; off <<= 1) {
        int u = (t >= off) ? s[t - off] : 0;
        __syncthreads();
        s[t] += u;
        __syncthreads();
    }
    const int excl = s[t] - tot;
    if (base + 0 < N) row_ptr[base + 0] = excl;
    if (base + 1 < N) row_ptr[base + 1] = excl + v0;
    if (base + 2 < N) row_ptr[base + 2] = excl + v0 + v1;
    if (base + 3 < N) row_ptr[base + 3] = excl + v0 + v1 + v2;
    if (t == 255) blk_sums[blockIdx.x] = s[255];
}

__global__ __launch_bounds__(256) void scan2_k(int* __restrict__ blk_sums, int NB,
                                               int* __restrict__ row_ptr, int N, int E) {
    __shared__ int s[256];
    const int t = threadIdx.x;
    const int v = (t < NB) ? blk_sums[t] : 0;
    s[t] = v;
    __syncthreads();
    for (int off = 1; off < 256; off <<= 1) {
        int u = (t >= off) ? s[t - off] : 0;
        __syncthreads();
        s[t] += u;
        __syncthreads();
    }
    if (t < NB) blk_sums[t] = s[t] - v;
    if (t == 0) row_ptr[N] = E;
}

__global__ __launch_bounds__(256) void scan3_k(int* __restrict__ row_ptr, int* __restrict__ cursor,
                                               const int* __restrict__ blk_sums, int N) {
    const int off = blk_sums[blockIdx.x];
    const int base = blockIdx.x * 1024 + threadIdx.x * 4;
#pragma unroll
    for (int j = 0; j < 4; ++j) {
        const int i = base + j;
        if (i < N) {
            const int v = row_ptr[i] + off;
            row_ptr[i] = v;
            cursor[i] = v;
        }
    }
}

__global__ void scatter_k(const int* __restrict__ src, const int* __restrict__ dst,
                          int* __restrict__ cursor, int* __restrict__ csr_src,
                          int* __restrict__ csr_eid, int E) {
    int t = blockIdx.x * 256 + threadIdx.x;
    if (t < E) {
        int d = dst[t];
        int pos = atomicAdd(&cursor[d], 1);
        csr_src[pos] = src[t];
        csr_eid[pos] = t;
    }
}

// ---------------- converts ----------------
__global__ __launch_bounds__(320) void cvt_uwp_k(const float* __restrict__ in, _Float16* __restrict__ out) {
    const int row = blockIdx.x;   // 0..383
    const int t = threadIdx.x;    // 0..319
    out[(size_t)row * 320 + t] = (_Float16)in[(size_t)row * D_IN + t];
}

__global__ void cvt_f32_k(const float* __restrict__ in, _Float16* __restrict__ out, int n) {
    int t = blockIdx.x * 256 + threadIdx.x;
    if (t < n) out[t] = (_Float16)in[t];
}

__global__ void cvt4_k(const float* __restrict__ in, _Float16* __restrict__ out, int n4) {
    int t = blockIdx.x * 256 + threadIdx.x;
    if (t < n4) {
        const f32x4 v = ((const f32x4*)in)[t];
        f16x4 r;
        r[0] = (_Float16)v[0]; r[1] = (_Float16)v[1];
        r[2] = (_Float16)v[2]; r[3] = (_Float16)v[3];
        ((f16x4*)out)[t] = r;
    }
}

__global__ void cvt_out_k(const _Float16* __restrict__ in, float* __restrict__ out, int n4) {
    int t = blockIdx.x * 256 + threadIdx.x;
    if (t < n4) {
        const f16x4 v = ((const f16x4*)in)[t];
        f32x4 r;
        r[0] = (float)v[0]; r[1] = (float)v[1];
        r[2] = (float)v[2]; r[3] = (float)v[3];
        ((f32x4*)out)[t] = r;
    }
}

// ---------------- c_k = U4*cond + U_b (fp32 exact) ----------------
__global__ void compute_c_k(const float* __restrict__ UW, const float* __restrict__ Ub,
                            const float* __restrict__ cond, float* __restrict__ cvec) {
    int t = threadIdx.x;
    if (t < 3 * D_NODE) {
        int k = t >> 7, i = t & 127;
        const float* u = UW + (size_t)k * D_NODE * D_IN + (size_t)i * D_IN + 320;
        cvec[t] = u[0] * cond[0] + u[1] * cond[1] + Ub[k * D_NODE + i];
    }
}

// ---------------- segment sums (CSR gather; fp32 acc -> fp16) ----------------
__global__ __launch_bounds__(256) void gather_e_k(const float* __restrict__ e,
                                                  const int* __restrict__ row_ptr,
                                                  const int* __restrict__ csr_eid,
                                                  _Float16* __restrict__ S_e, int N) {
    const int wave = threadIdx.x >> 6, lane = threadIdx.x & 63;
    const int n = blockIdx.x * 4 + wave;
    if (n >= N) return;
    const int p0 = row_ptr[n], p1 = row_ptr[n + 1];
    float a = 0.f, b = 0.f, c = 0.f, d = 0.f;
    int p = p0;
    for (; p + 3 < p1; p += 4) {
        const int e0 = csr_eid[p], e1 = csr_eid[p + 1], e2 = csr_eid[p + 2], e3 = csr_eid[p + 3];
        a += e[(size_t)e0 * D_EDGE + lane];
        b += e[(size_t)e1 * D_EDGE + lane];
        c += e[(size_t)e2 * D_EDGE + lane];
        d += e[(size_t)e3 * D_EDGE + lane];
    }
    for (; p < p1; ++p) a += e[(size_t)csr_eid[p] * D_EDGE + lane];
    S_e[(size_t)n * D_EDGE + lane] = (_Float16)((a + b) + (c + d));
}

__global__ __launch_bounds__(256) void gather_e16_k(const _Float16* __restrict__ e16,
                                                    const int* __restrict__ row_ptr,
                                                    const int* __restrict__ csr_eid,
                                                    _Float16* __restrict__ S_e, int N) {
    const int wave = threadIdx.x >> 6, lane = threadIdx.x & 63;
    const int half = lane >> 5, ln = lane & 31;
    const int n = blockIdx.x * 8 + wave * 2 + half;
    if (n >= N) return;
    const unsigned* ep = (const unsigned*)e16;
    const int p0 = row_ptr[n], p1 = row_ptr[n + 1];
    float a0 = 0.f, a1 = 0.f, b0 = 0.f, b1 = 0.f;
    float c0 = 0.f, c1 = 0.f, d0 = 0.f, d1 = 0.f;
    int p = p0;
    for (; p + 3 < p1; p += 4) {
        const int e0 = csr_eid[p], e1 = csr_eid[p + 1], e2 = csr_eid[p + 2], e3 = csr_eid[p + 3];
        const f16x2 v0 = __builtin_bit_cast(f16x2, ep[(size_t)e0 * 32 + ln]);
        const f16x2 v1 = __builtin_bit_cast(f16x2, ep[(size_t)e1 * 32 + ln]);
        const f16x2 v2 = __builtin_bit_cast(f16x2, ep[(size_t)e2 * 32 + ln]);
        const f16x2 v3 = __builtin_bit_cast(f16x2, ep[(size_t)e3 * 32 + ln]);
        a0 += (float)v0[0]; a1 += (float)v0[1];
        b0 += (float)v1[0]; b1 += (float)v1[1];
        c0 += (float)v2[0]; c1 += (float)v2[1];
        d0 += (float)v3[0]; d1 += (float)v3[1];
    }
    for (; p < p1; ++p) {
        const f16x2 v = __builtin_bit_cast(f16x2, ep[(size_t)csr_eid[p] * 32 + ln]);
        a0 += (float)v[0]; a1 += (float)v[1];
    }
    f16x2 r;
    r[0] = (_Float16)((a0 + b0) + (c0 + d0));
    r[1] = (_Float16)((a1 + b1) + (c1 + d1));
    ((unsigned*)S_e)[(size_t)n * 32 + ln] = __builtin_bit_cast(unsigned, r);
}

__global__ __launch_bounds__(256) void gather_h_k(const _Float16* __restrict__ h16,
                                                  const int* __restrict__ row_ptr,
                                                  const int* __restrict__ csr_src,
                                                  _Float16* __restrict__ S_h, int N) {
    const int wave = threadIdx.x >> 6, lane = threadIdx.x & 63;
    const int half = lane >> 5, ln = lane & 31;
    const int n = blockIdx.x * 8 + wave * 2 + half;
    if (n >= N) return;
    const uint2* hp = (const uint2*)h16;
    const int p0 = row_ptr[n], p1 = row_ptr[n + 1];
    float aA[4] = {0.f,0.f,0.f,0.f}, aB[4] = {0.f,0.f,0.f,0.f};
    float aC[4] = {0.f,0.f,0.f,0.f}, aD[4] = {0.f,0.f,0.f,0.f};
    int p = p0;
    for (; p + 3 < p1; p += 4) {
        const int s0 = csr_src[p], s1 = csr_src[p + 1], s2 = csr_src[p + 2], s3 = csr_src[p + 3];
        const f16x4 v0 = __builtin_bit_cast(f16x4, hp[(size_t)s0 * 32 + ln]);
        const f16x4 v1 = __builtin_bit_cast(f16x4, hp[(size_t)s1 * 32 + ln]);
        const f16x4 v2 = __builtin_bit_cast(f16x4, hp[(size_t)s2 * 32 + ln]);
        const f16x4 v3 = __builtin_bit_cast(f16x4, hp[(size_t)s3 * 32 + ln]);
#pragma unroll
        for (int j = 0; j < 4; ++j) {
            aA[j] += (float)v0[j]; aB[j] += (float)v1[j];
            aC[j] += (float)v2[j]; aD[j] += (float)v3[j];
        }
    }
    for (; p < p1; ++p) {
        const f16x4 v = __builtin_bit_cast(f16x4, hp[(size_t)csr_src[p] * 32 + ln]);
#pragma unroll
        for (int j = 0; j < 4; ++j) aA[j] += (float)v[j];
    }
    f16x4 r;
#pragma unroll
    for (int j = 0; j < 4; ++j) r[j] = (_Float16)((aA[j] + aB[j]) + (aC[j] + aD[j]));
    ((uint2*)S_h)[(size_t)n * 32 + ln] = __builtin_bit_cast(uint2, r);
}

// ---------------- agg kernel: barrier-free, wave w <-> nb=w, B pinned in registers ----------------
__global__ __launch_bounds__(512, 1) void agg_k(
    const _Float16* __restrict__ hcur,
    const _Float16* __restrict__ S_h,
    const _Float16* __restrict__ S_e,
    const int* __restrict__ row_ptr,
    const float* __restrict__ cvec,
    const _Float16* __restrict__ UWp,   // [128][320] fp16, this round's slice
    _Float16* __restrict__ agg,
    int N) {
    const int tid  = threadIdx.x;
    const int wave = tid >> 6;          // = nb
    const int lane = tid & 63;
    const int l15  = lane & 15;
    const int lg   = lane >> 4;
    const int c0   = wave * 16 + l15;   // output col
    const int row0 = blockIdx.x * MROWS;

    const unsigned short* hp  = (const unsigned short*)hcur;
    const unsigned short* shp = (const unsigned short*)S_h;
    const unsigned short* sep = (const unsigned short*)S_e;
    const unsigned short* uwp = (const unsigned short*)UWp;

    // B fragments for this wave's col-block: K = 0..320 (U1|U2|U3); pinned.
    f16x8 Bu[10];
#pragma unroll
    for (int kb = 0; kb < 10; ++kb)
        Bu[kb] = as_f16x8(*(const u16x8*)(uwp + (size_t)c0 * 320 + kb * 32 + lg * 8));
#pragma unroll
    for (int kb = 0; kb < 10; ++kb) KEEPV(Bu[kb]);
    const float cv = cvec[c0];

#pragma unroll 1
    for (int m = 0; m < MROWS / 16; ++m) {
        const int r16 = row0 + m * 16;
        const int arow = min(r16 + l15, N - 1);
        f16x8 a_h[4], a_sh[4], a_se[2];
#pragma unroll
        for (int kb = 0; kb < 4; ++kb) {
            a_h[kb]  = as_f16x8(*(const u16x8*)(hp  + (size_t)arow * D_NODE + kb * 32 + lg * 8));
            a_sh[kb] = as_f16x8(*(const u16x8*)(shp + (size_t)arow * D_NODE + kb * 32 + lg * 8));
        }
#pragma unroll
        for (int kb = 0; kb < 2; ++kb)
            a_se[kb] = as_f16x8(*(const u16x8*)(sep + (size_t)arow * D_EDGE + kb * 32 + lg * 8));
        float degv[4];
#pragma unroll
        for (int i = 0; i < 4; ++i) {
            const int n = min(r16 + lg * 4 + i, N - 1);
            degv[i] = (float)(row_ptr[n + 1] - row_ptr[n]);
        }

        f32x4 acc1 = {0.f,0.f,0.f,0.f}, acc2 = {0.f,0.f,0.f,0.f};
#pragma unroll
        for (int kb = 0; kb < 4; ++kb)
            acc1 = __builtin_amdgcn_mfma_f32_16x16x32_f16(a_h[kb], Bu[kb], acc1, 0, 0, 0);
#pragma unroll
        for (int kb = 0; kb < 4; ++kb)
            acc2 = __builtin_amdgcn_mfma_f32_16x16x32_f16(a_sh[kb], Bu[4 + kb], acc2, 0, 0, 0);
#pragma unroll
        for (int kb = 0; kb < 2; ++kb)
            acc2 = __builtin_amdgcn_mfma_f32_16x16x32_f16(a_se[kb], Bu[8 + kb], acc2, 0, 0, 0);

#pragma unroll
        for (int i = 0; i < 4; ++i) {
            const int n = r16 + lg * 4 + i;
            if (n < N)
                agg[(size_t)n * D_NODE + c0] = (_Float16)(degv[i] * (acc1[i] + cv) + acc2[i]);
        }
    }
}

// ---------------- GRU kernel: barrier-free, wave w <-> nb=w, B pinned in registers ----------------
// Reads hcur (frags + hv), writes hnext (ping-pong; removes in-place RAW hazard).
__global__ __launch_bounds__(512, 1) void gru_k(
    const _Float16* __restrict__ hcur,
    _Float16* __restrict__ hnext,
    const _Float16* __restrict__ agg,
    const _Float16* __restrict__ Wihh,  // [384][128] fp16
    const _Float16* __restrict__ Whhh,  // [384][128] fp16
    const float* __restrict__ bih,
    const float* __restrict__ bhh,
    int N) {
    const int tid  = threadIdx.x;
    const int wave = tid >> 6;          // = nb
    const int lane = tid & 63;
    const int l15  = lane & 15;
    const int lg   = lane >> 4;
    const int c0   = wave * 16 + l15;   // output col
    const int row0 = blockIdx.x * MROWS;

    const unsigned short* hp  = (const unsigned short*)hcur;
    const unsigned short* agp = (const unsigned short*)agg;
    const unsigned short* wih = (const unsigned short*)Wihh;
    const unsigned short* whh = (const unsigned short*)Whhh;

    // B fragments: 6 gate matrices x 4 kb, col = c0 (+gate offsets); pinned.
    f16x8 B[6][4];
#pragma unroll
    for (int g = 0; g < 3; ++g)
#pragma unroll
        for (int kb = 0; kb < 4; ++kb)
            B[g][kb] = as_f16x8(*(const u16x8*)(wih + (size_t)(c0 + g * 128) * D_NODE + kb * 32 + lg * 8));
#pragma unroll
    for (int g = 0; g < 3; ++g)
#pragma unroll
        for (int kb = 0; kb < 4; ++kb)
            B[3 + g][kb] = as_f16x8(*(const u16x8*)(whh + (size_t)(c0 + g * 128) * D_NODE + kb * 32 + lg * 8));
#pragma unroll
    for (int g = 0; g < 6; ++g)
#pragma unroll
        for (int kb = 0; kb < 4; ++kb) KEEPV(B[g][kb]);

    const float bir = bih[c0],       biz = bih[128 + c0], bin = bih[256 + c0];
    const float bhr = bhh[c0],       bhz = bhh[128 + c0], bhn = bhh[256 + c0];

#pragma unroll 1
    for (int m = 0; m < MROWS / 16; ++m) {
        const int r16 = row0 + m * 16;
        const int arow = min(r16 + l15, N - 1);
        f16x8 a_ag[4], a_h[4];
#pragma unroll
        for (int kb = 0; kb < 4; ++kb) {
            a_ag[kb] = as_f16x8(*(const u16x8*)(agp + (size_t)arow * D_NODE + kb * 32 + lg * 8));
            a_h[kb]  = as_f16x8(*(const u16x8*)(hp  + (size_t)arow * D_NODE + kb * 32 + lg * 8));
        }
        float hv[4];
#pragma unroll
        for (int i = 0; i < 4; ++i) {
            const int n = min(r16 + lg * 4 + i, N - 1);
            hv[i] = (float)hcur[(size_t)n * D_NODE + c0];
        }

        f32x4 air = {0.f,0.f,0.f,0.f}, aiz = {0.f,0.f,0.f,0.f}, ain_ = {0.f,0.f,0.f,0.f};
        f32x4 ahr = {0.f,0.f,0.f,0.f}, ahz = {0.f,0.f,0.f,0.f}, ahn = {0.f,0.f,0.f,0.f};
#pragma unroll
        for (int kb = 0; kb < 4; ++kb) {
            air  = __builtin_amdgcn_mfma_f32_16x16x32_f16(a_ag[kb], B[0][kb], air, 0, 0, 0);
            aiz  = __builtin_amdgcn_mfma_f32_16x16x32_f16(a_ag[kb], B[1][kb], aiz, 0, 0, 0);
            ain_ = __builtin_amdgcn_mfma_f32_16x16x32_f16(a_ag[kb], B[2][kb], ain_, 0, 0, 0);
            ahr  = __builtin_amdgcn_mfma_f32_16x16x32_f16(a_h[kb],  B[3][kb], ahr, 0, 0, 0);
            ahz  = __builtin_amdgcn_mfma_f32_16x16x32_f16(a_h[kb],  B[4][kb], ahz, 0, 0, 0);
            ahn  = __builtin_amdgcn_mfma_f32_16x16x32_f16(a_h[kb],  B[5][kb], ahn, 0, 0, 0);
        }

#pragma unroll
        for (int i = 0; i < 4; ++i) {
            const int n = r16 + lg * 4 + i;
            if (n < N) {
                const float r  = sigm_(air[i] + bir + ahr[i] + bhr);
                const float z  = sigm_(aiz[i] + biz + ahz[i] + bhz);
                const float nn = tanh_(ain_[i] + bin + r * (ahn[i] + bhn));
                hnext[(size_t)n * D_NODE + c0] = (_Float16)((1.f - z) * nn + z * hv[i]);
            }
        }
    }
}

// ---------------- launch ----------------
extern "C" void kernel_launch(void* const* d_in, const int* in_sizes, int n_in,
                              void* d_out, int out_size, void* d_ws, size_t ws_size,
                              hipStream_t stream) {
    const float* h0   = (const float*)d_in[0];
    const float* e    = (const float*)d_in[1];
    const int*   src  = (const int*)d_in[2];
    const int*   dst  = (const int*)d_in[3];
    const float* cond = (const float*)d_in[4];
    const float* UW   = (const float*)d_in[5];
    const float* Ub   = (const float*)d_in[6];
    const float* Wih  = (const float*)d_in[7];
    const float* Whh  = (const float*)d_in[8];
    const float* bih  = (const float*)d_in[9];
    const float* bhh  = (const float*)d_in[10];

    const int N = in_sizes[0] / D_NODE;
    const int E = in_sizes[2];
    const int NB = (N + 1023) / 1024;
    const int NT = (N + MROWS - 1) / MROWS;

    char* wsb = (char*)d_ws;
    size_t off = 0;
    auto carve = [&](size_t bytes) -> char* {
        char* p = wsb + off;
        off = (off + bytes + 255) & ~(size_t)255;
        return p;
    };
    int*   cnt      = (int*)carve((size_t)N * 4);
    int*   row_ptr  = (int*)carve(((size_t)N + 1) * 4);
    int*   cursor   = (int*)carve((size_t)N * 4);
    int*   csr_src  = (int*)carve((size_t)E * 4);
    int*   csr_eid  = (int*)carve((size_t)E * 4);
    int*   blk_sums = (int*)carve(256 * 4);
    float* cvec     = (float*)carve(3 * D_NODE * 4);
    _Float16* S_e  = (_Float16*)carve((size_t)N * D_EDGE * 2);
    _Float16* S_h  = (_Float16*)carve((size_t)N * D_NODE * 2);
    _Float16* aggb = (_Float16*)carve((size_t)N * D_NODE * 2);
    _Float16* h16a = (_Float16*)carve((size_t)N * D_NODE * 2);
    _Float16* h16b = (_Float16*)carve((size_t)N * D_NODE * 2);
    _Float16* UWp  = (_Float16*)carve((size_t)3 * D_NODE * 320 * 2);
    _Float16* Wihh = (_Float16*)carve((size_t)3 * GRU3 * D_NODE * 2);
    _Float16* Whhh = (_Float16*)carve((size_t)3 * GRU3 * D_NODE * 2);
    const size_t e16_bytes = (size_t)E * D_EDGE * 2;
    _Float16* e16 = nullptr;
    if (off + e16_bytes + 256 <= ws_size) e16 = (_Float16*)carve(e16_bytes);
    (void)n_in; (void)out_size;

    hipMemsetAsync(cnt, 0, (size_t)N * 4, stream);
    hist_k<<<(E + 255) / 256, 256, 0, stream>>>(dst, cnt, E);
    scan1_k<<<NB, 256, 0, stream>>>(cnt, row_ptr, blk_sums, N);
    scan2_k<<<1, 256, 0, stream>>>(blk_sums, NB, row_ptr, N, E);
    scan3_k<<<NB, 256, 0, stream>>>(row_ptr, cursor, blk_sums, N);
    scatter_k<<<(E + 255) / 256, 256, 0, stream>>>(src, dst, cursor, csr_src, csr_eid, E);
    compute_c_k<<<1, 384, 0, stream>>>(UW, Ub, cond, cvec);
    cvt_uwp_k<<<3 * D_NODE, 320, 0, stream>>>(UW, UWp);
    {
        const int n1 = 3 * GRU3 * D_NODE;
        cvt_f32_k<<<(n1 + 255) / 256, 256, 0, stream>>>(Wih, Wihh, n1);
        cvt_f32_k<<<(n1 + 255) / 256, 256, 0, stream>>>(Whh, Whhh, n1);
    }
    {
        const int n4 = N * D_NODE / 4;
        cvt4_k<<<(n4 + 255) / 256, 256, 0, stream>>>(h0, h16a, n4);   // seed fp16 state
    }
    if (e16) {
        const int n4 = E * D_EDGE / 4;
        cvt4_k<<<(n4 + 255) / 256, 256, 0, stream>>>(e, e16, n4);
        gather_e16_k<<<(N + 7) / 8, 256, 0, stream>>>(e16, row_ptr, csr_eid, S_e, N);
    } else {
        gather_e_k<<<(N + 3) / 4, 256, 0, stream>>>(e, row_ptr, csr_eid, S_e, N);
    }

    _Float16* hcur = h16a;
    _Float16* hnext = h16b;
    for (int k = 0; k < 3; ++k) {
        gather_h_k<<<(N + 7) / 8, 256, 0, stream>>>(hcur, row_ptr, csr_src, S_h, N);
        agg_k<<<NT, 512, 0, stream>>>(
            hcur, S_h, S_e, row_ptr, cvec + k * D_NODE,
            UWp + (size_t)k * D_NODE * 320, aggb, N);
        gru_k<<<NT, 512, 0, stream>>>(
            hcur, hnext, aggb,
            Wihh + (size_t)k * GRU3 * D_NODE,
            Whhh + (size_t)k * GRU3 * D_NODE,
            bih + (size_t)k * GRU3,
            bhh + (size_t)k * GRU3,
            N);
        _Float16* t = hcur; hcur = hnext; hnext = t;
    }
    {
        const int n4 = N * D_NODE / 4;
        cvt_out_k<<<(n4 + 255) / 256, 256, 0, stream>>>(hcur, (float*)d_out, n4);
    }
}

// Round 17
// 535.095 us; speedup vs baseline: 1.4447x; 1.4447x over previous
//
#include <hip/hip_runtime.h>
#include <hip/hip_bf16.h>
#include <hip/hip_fp16.h>

// GGM encode, decomposed (inputs fp32; internal fp16 MFMA, fp32 accum; output fp32):
//   agg[v] = deg(v)*(U1 h_v + c_k) + U2*S_h[v] + U3*S_e[v]
//   GRU: gi = agg@Wih^T + bih, gh = h@Whh^T + bhh, fused elementwise in fp32.
// R16->R17: REVERT to R14 (best: 536us). R15/R16 proved the barrier-free
// register-B design cannot be pinned at HIP level (VGPR stuck at 84, remat/spill).
// R14 config: 512-thr panel kernels, LB(512,2) => 128-VGPR cap, double-buffered
// LDS weight panels, one barrier/nb, h16-only GRU state, 2-nodes/wave gathers.

#define D_NODE 128
#define D_EDGE 64
#define D_IN   322
#define GRU3   384
#define ROWS_BLK 256    // rows per (512-thread) MFMA block
#define PA_STRIDE 328   // panel-A row stride (elems): 656B
#define PB_STRIDE 136   // panel-B row stride (elems): 272B

typedef _Float16 f16x8 __attribute__((ext_vector_type(8)));
typedef _Float16 f16x4 __attribute__((ext_vector_type(4)));
typedef _Float16 f16x2 __attribute__((ext_vector_type(2)));
typedef float    f32x4 __attribute__((ext_vector_type(4)));
typedef unsigned short u16x8 __attribute__((ext_vector_type(8)));

__device__ __forceinline__ f16x8 as_f16x8(u16x8 v) { return __builtin_bit_cast(f16x8, v); }
__device__ __forceinline__ float sigm_(float x) { return 1.f / (1.f + __expf(-x)); }
__device__ __forceinline__ float tanh_(float x) { return 1.f - 2.f / (__expf(2.f * x) + 1.f); }

// ---------------- CSR build ----------------
__global__ void hist_k(const int* __restrict__ dst, int* __restrict__ cnt, int E) {
    int t = blockIdx.x * 256 + threadIdx.x;
    if (t < E) atomicAdd(&cnt[dst[t]], 1);
}

__global__ __launch_bounds__(256) void scan1_k(const int* __restrict__ cnt, int* __restrict__ row_ptr,
                                               int* __restrict__ blk_sums, int N) {
    __shared__ int s[256];
    const int t = threadIdx.x;
    const int base = blockIdx.x * 1024 + t * 4;
    int v0 = (base + 0 < N) ? cnt[base + 0] : 0;
    int v1 = (base + 1 < N) ? cnt[base + 1] : 0;
    int v2 = (base + 2 < N) ? cnt[base + 2] : 0;
    int v3 = (base + 3 < N) ? cnt[base + 3] : 0;
    const int tot = v0 + v1 + v2 + v3;
    s[t] = tot;
    __syncthreads();
    for (int off = 1; off < 256; off <<= 1) {
        int u = (t >= off) ? s[t - off] : 0;
        __syncthreads();
        s[t] += u;
        __syncthreads();
    }
    const int excl = s[t] - tot;
    if (base + 0 < N) row_ptr[base + 0] = excl;
    if (base + 1 < N) row_ptr[base + 1] = excl + v0;
    if (base + 2 < N) row_ptr[base + 2] = excl + v0 + v1;
    if (base + 3 < N) row_ptr[base + 3] = excl + v0 + v1 + v2;
    if (t == 255) blk_sums[blockIdx.x] = s[255];
}

__global__ __launch_bounds__(256) void scan2_k(int* __restrict__ blk_sums, int NB,
                                               int* __restrict__ row_ptr, int N, int E) {
    __shared__ int s[256];
    const int t = threadIdx.x;
    const int v = (t < NB) ? blk_sums[t] : 0;
    s[t] = v;
    __syncthreads();
    for (int off = 1; off < 256; off <<= 1) {
        int u = (t >= off) ? s[t - off] : 0;
        __syncthreads();
        s[t] += u;
        __syncthreads();
    }
    if (t < NB) blk_sums[t] = s[t] - v;
    if (t == 0) row_ptr[N] = E;
}

__global__ __launch_bounds__(256) void scan3_k(int* __restrict__ row_ptr, int* __restrict__ cursor,
                                               const int* __restrict__ blk_sums, int N) {
    const int off = blk_sums[blockIdx.x];
    const int base = blockIdx.x * 1024 + threadIdx.x * 4;
#pragma unroll
    for (int j = 0; j < 4; ++j) {
        const int i = base + j;
        if (i < N) {
            const int v = row_ptr[i] + off;
            row_ptr[i] = v;
            cursor[i] = v;
        }
    }
}

__global__ void scatter_k(const int* __restrict__ src, const int* __restrict__ dst,
                          int* __restrict__ cursor, int* __restrict__ csr_src,
                          int* __restrict__ csr_eid, int E) {
    int t = blockIdx.x * 256 + threadIdx.x;
    if (t < E) {
        int d = dst[t];
        int pos = atomicAdd(&cursor[d], 1);
        csr_src[pos] = src[t];
        csr_eid[pos] = t;
    }
}

// ---------------- converts ----------------
__global__ __launch_bounds__(320) void cvt_uwp_k(const float* __restrict__ in, _Float16* __restrict__ out) {
    const int row = blockIdx.x;   // 0..383
    const int t = threadIdx.x;    // 0..319
    out[(size_t)row * 320 + t] = (_Float16)in[(size_t)row * D_IN + t];
}

__global__ void cvt_f32_k(const float* __restrict__ in, _Float16* __restrict__ out, int n) {
    int t = blockIdx.x * 256 + threadIdx.x;
    if (t < n) out[t] = (_Float16)in[t];
}

__global__ void cvt4_k(const float* __restrict__ in, _Float16* __restrict__ out, int n4) {
    int t = blockIdx.x * 256 + threadIdx.x;
    if (t < n4) {
        const f32x4 v = ((const f32x4*)in)[t];
        f16x4 r;
        r[0] = (_Float16)v[0]; r[1] = (_Float16)v[1];
        r[2] = (_Float16)v[2]; r[3] = (_Float16)v[3];
        ((f16x4*)out)[t] = r;
    }
}

__global__ void cvt_out_k(const _Float16* __restrict__ in, float* __restrict__ out, int n4) {
    int t = blockIdx.x * 256 + threadIdx.x;
    if (t < n4) {
        const f16x4 v = ((const f16x4*)in)[t];
        f32x4 r;
        r[0] = (float)v[0]; r[1] = (float)v[1];
        r[2] = (float)v[2]; r[3] = (float)v[3];
        ((f32x4*)out)[t] = r;
    }
}

// ---------------- c_k = U4*cond + U_b (fp32 exact) ----------------
__global__ void compute_c_k(const float* __restrict__ UW, const float* __restrict__ Ub,
                            const float* __restrict__ cond, float* __restrict__ cvec) {
    int t = threadIdx.x;
    if (t < 3 * D_NODE) {
        int k = t >> 7, i = t & 127;
        const float* u = UW + (size_t)k * D_NODE * D_IN + (size_t)i * D_IN + 320;
        cvec[t] = u[0] * cond[0] + u[1] * cond[1] + Ub[k * D_NODE + i];
    }
}

// ---------------- segment sums: 2 nodes/wave (32 lanes per node) ----------------
__global__ __launch_bounds__(256) void gather_e_k(const float* __restrict__ e,
                                                  const int* __restrict__ row_ptr,
                                                  const int* __restrict__ csr_eid,
                                                  _Float16* __restrict__ S_e, int N) {
    const int wave = threadIdx.x >> 6, lane = threadIdx.x & 63;
    const int n = blockIdx.x * 4 + wave;
    if (n >= N) return;
    const int p0 = row_ptr[n], p1 = row_ptr[n + 1];
    float a = 0.f, b = 0.f, c = 0.f, d = 0.f;
    int p = p0;
    for (; p + 3 < p1; p += 4) {
        const int e0 = csr_eid[p], e1 = csr_eid[p + 1], e2 = csr_eid[p + 2], e3 = csr_eid[p + 3];
        a += e[(size_t)e0 * D_EDGE + lane];
        b += e[(size_t)e1 * D_EDGE + lane];
        c += e[(size_t)e2 * D_EDGE + lane];
        d += e[(size_t)e3 * D_EDGE + lane];
    }
    for (; p < p1; ++p) a += e[(size_t)csr_eid[p] * D_EDGE + lane];
    S_e[(size_t)n * D_EDGE + lane] = (_Float16)((a + b) + (c + d));
}

__global__ __launch_bounds__(256) void gather_e16_k(const _Float16* __restrict__ e16,
                                                    const int* __restrict__ row_ptr,
                                                    const int* __restrict__ csr_eid,
                                                    _Float16* __restrict__ S_e, int N) {
    const int wave = threadIdx.x >> 6, lane = threadIdx.x & 63;
    const int half = lane >> 5, ln = lane & 31;
    const int n = blockIdx.x * 8 + wave * 2 + half;
    if (n >= N) return;
    const unsigned* ep = (const unsigned*)e16;   // 32 u32 per row
    const int p0 = row_ptr[n], p1 = row_ptr[n + 1];
    float a0 = 0.f, a1 = 0.f, b0 = 0.f, b1 = 0.f;
    float c0 = 0.f, c1 = 0.f, d0 = 0.f, d1 = 0.f;
    int p = p0;
    for (; p + 3 < p1; p += 4) {
        const int e0 = csr_eid[p], e1 = csr_eid[p + 1], e2 = csr_eid[p + 2], e3 = csr_eid[p + 3];
        const f16x2 v0 = __builtin_bit_cast(f16x2, ep[(size_t)e0 * 32 + ln]);
        const f16x2 v1 = __builtin_bit_cast(f16x2, ep[(size_t)e1 * 32 + ln]);
        const f16x2 v2 = __builtin_bit_cast(f16x2, ep[(size_t)e2 * 32 + ln]);
        const f16x2 v3 = __builtin_bit_cast(f16x2, ep[(size_t)e3 * 32 + ln]);
        a0 += (float)v0[0]; a1 += (float)v0[1];
        b0 += (float)v1[0]; b1 += (float)v1[1];
        c0 += (float)v2[0]; c1 += (float)v2[1];
        d0 += (float)v3[0]; d1 += (float)v3[1];
    }
    for (; p < p1; ++p) {
        const f16x2 v = __builtin_bit_cast(f16x2, ep[(size_t)csr_eid[p] * 32 + ln]);
        a0 += (float)v[0]; a1 += (float)v[1];
    }
    f16x2 r;
    r[0] = (_Float16)((a0 + b0) + (c0 + d0));
    r[1] = (_Float16)((a1 + b1) + (c1 + d1));
    ((unsigned*)S_e)[(size_t)n * 32 + ln] = __builtin_bit_cast(unsigned, r);
}

__global__ __launch_bounds__(256) void gather_h_k(const _Float16* __restrict__ h16,
                                                  const int* __restrict__ row_ptr,
                                                  const int* __restrict__ csr_src,
                                                  _Float16* __restrict__ S_h, int N) {
    const int wave = threadIdx.x >> 6, lane = threadIdx.x & 63;
    const int half = lane >> 5, ln = lane & 31;
    const int n = blockIdx.x * 8 + wave * 2 + half;
    if (n >= N) return;
    const uint2* hp = (const uint2*)h16;   // 32 uint2 per row
    const int p0 = row_ptr[n], p1 = row_ptr[n + 1];
    float aA[4] = {0.f,0.f,0.f,0.f}, aB[4] = {0.f,0.f,0.f,0.f};
    float aC[4] = {0.f,0.f,0.f,0.f}, aD[4] = {0.f,0.f,0.f,0.f};
    int p = p0;
    for (; p + 3 < p1; p += 4) {
        const int s0 = csr_src[p], s1 = csr_src[p + 1], s2 = csr_src[p + 2], s3 = csr_src[p + 3];
        const f16x4 v0 = __builtin_bit_cast(f16x4, hp[(size_t)s0 * 32 + ln]);
        const f16x4 v1 = __builtin_bit_cast(f16x4, hp[(size_t)s1 * 32 + ln]);
        const f16x4 v2 = __builtin_bit_cast(f16x4, hp[(size_t)s2 * 32 + ln]);
        const f16x4 v3 = __builtin_bit_cast(f16x4, hp[(size_t)s3 * 32 + ln]);
#pragma unroll
        for (int j = 0; j < 4; ++j) {
            aA[j] += (float)v0[j]; aB[j] += (float)v1[j];
            aC[j] += (float)v2[j]; aD[j] += (float)v3[j];
        }
    }
    for (; p < p1; ++p) {
        const f16x4 v = __builtin_bit_cast(f16x4, hp[(size_t)csr_src[p] * 32 + ln]);
#pragma unroll
        for (int j = 0; j < 4; ++j) aA[j] += (float)v[j];
    }
    f16x4 r;
#pragma unroll
    for (int j = 0; j < 4; ++j) r[j] = (_Float16)((aA[j] + aB[j]) + (aC[j] + aD[j]));
    ((uint2*)S_h)[(size_t)n * 32 + ln] = __builtin_bit_cast(uint2, r);
}

// ---------------- agg kernel (512 thr, 8 waves, 256 rows/block) ----------------
__global__ __launch_bounds__(512, 2) void agg_k(
    const _Float16* __restrict__ h16,
    const _Float16* __restrict__ S_h,
    const _Float16* __restrict__ S_e,
    const int* __restrict__ row_ptr,
    const float* __restrict__ cvec,
    const _Float16* __restrict__ UWp,   // [128][320] fp16, this round's slice
    _Float16* __restrict__ agg,
    int N) {
    __shared__ __align__(16) _Float16 pbuf[2][16 * PA_STRIDE];  // 2 x 10.5 KB

    const int tid  = threadIdx.x;
    const int wave = tid >> 6;
    const int lane = tid & 63;
    const int l15  = lane & 15;
    const int lg   = lane >> 4;
    const int rbase = blockIdx.x * ROWS_BLK + wave * 32;

    const unsigned short* hp  = (const unsigned short*)h16;
    const unsigned short* shp = (const unsigned short*)S_h;
    const unsigned short* sep = (const unsigned short*)S_e;
    const unsigned short* uwp = (const unsigned short*)UWp;

    f16x8 a_h[2][4], a_sh[2][4], a_se[2][2];
#pragma unroll
    for (int m = 0; m < 2; ++m) {
        const int arow = min(rbase + m * 16 + l15, N - 1);
#pragma unroll
        for (int kb = 0; kb < 4; ++kb) {
            a_h[m][kb]  = as_f16x8(*(const u16x8*)(hp  + (size_t)arow * D_NODE + kb * 32 + lg * 8));
            a_sh[m][kb] = as_f16x8(*(const u16x8*)(shp + (size_t)arow * D_NODE + kb * 32 + lg * 8));
        }
#pragma unroll
        for (int kb = 0; kb < 2; ++kb)
            a_se[m][kb] = as_f16x8(*(const u16x8*)(sep + (size_t)arow * D_EDGE + kb * 32 + lg * 8));
    }
    float degv[2][4];
#pragma unroll
    for (int m = 0; m < 2; ++m)
#pragma unroll
        for (int i = 0; i < 4; ++i) {
            const int n = min(rbase + m * 16 + lg * 4 + i, N - 1);
            degv[m][i] = (float)(row_ptr[n + 1] - row_ptr[n]);
        }

    // panel staging: 640 16B-chunks; 512 threads -> chunk tid (all) + 512+tid (tid<128)
    u16x8 pr0, pr1;
    auto load_panel = [&](int nb) {
        const int c0 = tid, c1 = 512 + tid;
        pr0 = *(const u16x8*)(uwp + (size_t)(nb * 16 + c0 / 40) * 320 + (c0 % 40) * 8);
        if (c1 < 640)
            pr1 = *(const u16x8*)(uwp + (size_t)(nb * 16 + c1 / 40) * 320 + (c1 % 40) * 8);
    };
    auto write_panel = [&](int b) {
        const int c0 = tid, c1 = 512 + tid;
        *(u16x8*)&pbuf[b][(c0 / 40) * PA_STRIDE + (c0 % 40) * 8] = pr0;
        if (c1 < 640)
            *(u16x8*)&pbuf[b][(c1 / 40) * PA_STRIDE + (c1 % 40) * 8] = pr1;
    };

    load_panel(0);
    write_panel(0);
    __syncthreads();

#pragma unroll 1
    for (int nb = 0; nb < 8; ++nb) {
        if (nb < 7) load_panel(nb + 1);
        const _Float16* bp = pbuf[nb & 1];
        f32x4 acc1[2] = {{0.f,0.f,0.f,0.f},{0.f,0.f,0.f,0.f}};
        f32x4 acc2[2] = {{0.f,0.f,0.f,0.f},{0.f,0.f,0.f,0.f}};
#pragma unroll
        for (int kb = 0; kb < 10; ++kb) {
            f16x8 b = as_f16x8(*(const u16x8*)&bp[l15 * PA_STRIDE + kb * 32 + lg * 8]);
            if (kb < 4) {
                acc1[0] = __builtin_amdgcn_mfma_f32_16x16x32_f16(a_h[0][kb], b, acc1[0], 0, 0, 0);
                acc1[1] = __builtin_amdgcn_mfma_f32_16x16x32_f16(a_h[1][kb], b, acc1[1], 0, 0, 0);
            } else if (kb < 8) {
                acc2[0] = __builtin_amdgcn_mfma_f32_16x16x32_f16(a_sh[0][kb-4], b, acc2[0], 0, 0, 0);
                acc2[1] = __builtin_amdgcn_mfma_f32_16x16x32_f16(a_sh[1][kb-4], b, acc2[1], 0, 0, 0);
            } else {
                acc2[0] = __builtin_amdgcn_mfma_f32_16x16x32_f16(a_se[0][kb-8], b, acc2[0], 0, 0, 0);
                acc2[1] = __builtin_amdgcn_mfma_f32_16x16x32_f16(a_se[1][kb-8], b, acc2[1], 0, 0, 0);
            }
        }
        const float cv = cvec[nb * 16 + l15];
#pragma unroll
        for (int m = 0; m < 2; ++m)
#pragma unroll
            for (int i = 0; i < 4; ++i) {
                const int n = rbase + m * 16 + lg * 4 + i;
                if (n < N)
                    agg[(size_t)n * D_NODE + nb * 16 + l15] =
                        (_Float16)(degv[m][i] * (acc1[m][i] + cv) + acc2[m][i]);
            }
        if (nb < 7) write_panel((nb + 1) & 1);
        __syncthreads();
    }
}

// ---------------- GRU kernel (512 thr, 8 waves, 256 rows/block; fp16-state) ----------------
__global__ __launch_bounds__(512, 2) void gru_k(
    _Float16* __restrict__ h16,          // read frags + hv; write fp16(h') in-place
    const _Float16* __restrict__ agg,
    const _Float16* __restrict__ Wihh,  // [384][128] fp16
    const _Float16* __restrict__ Whhh,  // [384][128] fp16
    const float* __restrict__ bih,
    const float* __restrict__ bhh,
    int N) {
    __shared__ __align__(16) _Float16 pbuf[2][96 * PB_STRIDE];  // 2 x 25.5 KB

    const int tid  = threadIdx.x;
    const int wave = tid >> 6;
    const int lane = tid & 63;
    const int l15  = lane & 15;
    const int lg   = lane >> 4;
    const int rbase = blockIdx.x * ROWS_BLK + wave * 32;

    const unsigned short* hp  = (const unsigned short*)h16;
    const unsigned short* agp = (const unsigned short*)agg;
    const unsigned short* wih = (const unsigned short*)Wihh;
    const unsigned short* whh = (const unsigned short*)Whhh;

    f16x8 a_ag[2][4], a_h[2][4];
#pragma unroll
    for (int m = 0; m < 2; ++m) {
        const int arow = min(rbase + m * 16 + l15, N - 1);
#pragma unroll
        for (int kb = 0; kb < 4; ++kb) {
            a_ag[m][kb] = as_f16x8(*(const u16x8*)(agp + (size_t)arow * D_NODE + kb * 32 + lg * 8));
            a_h[m][kb]  = as_f16x8(*(const u16x8*)(hp  + (size_t)arow * D_NODE + kb * 32 + lg * 8));
        }
    }

    // panel staging: 1536 16B-chunks = 3 rounds x 512 thr (exact)
    u16x8 pr[3];
    auto load_panel = [&](int nb) {
#pragma unroll
        for (int r = 0; r < 3; ++r) {
            const int c = r * 512 + tid;
            const int row = c >> 4;            // 0..95
            const int off = (c & 15) * 8;      // elems
            const int gate = row >> 4;         // 0..5
            const int col = nb * 16 + (row & 15) + (gate % 3) * D_NODE;
            const unsigned short* mat = (gate < 3) ? wih : whh;
            pr[r] = *(const u16x8*)(mat + (size_t)col * D_NODE + off);
        }
    };
    auto write_panel = [&](int b) {
#pragma unroll
        for (int r = 0; r < 3; ++r) {
            const int c = r * 512 + tid;
            const int row = c >> 4;
            const int off = (c & 15) * 8;
            *(u16x8*)&pbuf[b][row * PB_STRIDE + off] = pr[r];
        }
    };

    load_panel(0);
    write_panel(0);
    __syncthreads();

#pragma unroll 1
    for (int nb = 0; nb < 8; ++nb) {
        if (nb < 7) load_panel(nb + 1);
        const int d = nb * 16 + l15;
        float hv[2][4];
#pragma unroll
        for (int m = 0; m < 2; ++m)
#pragma unroll
            for (int i = 0; i < 4; ++i) {
                const int n = min(rbase + m * 16 + lg * 4 + i, N - 1);
                hv[m][i] = (float)h16[(size_t)n * D_NODE + d];
            }
        const float bir = bih[d],       biz = bih[128 + d], bin = bih[256 + d];
        const float bhr = bhh[d],       bhz = bhh[128 + d], bhn = bhh[256 + d];

        const _Float16* bp = pbuf[nb & 1];
        f32x4 air[2] = {{0.f,0.f,0.f,0.f},{0.f,0.f,0.f,0.f}};
        f32x4 aiz[2] = {{0.f,0.f,0.f,0.f},{0.f,0.f,0.f,0.f}};
        f32x4 ain_[2] = {{0.f,0.f,0.f,0.f},{0.f,0.f,0.f,0.f}};
        f32x4 ahr[2] = {{0.f,0.f,0.f,0.f},{0.f,0.f,0.f,0.f}};
        f32x4 ahz[2] = {{0.f,0.f,0.f,0.f},{0.f,0.f,0.f,0.f}};
        f32x4 ahn[2] = {{0.f,0.f,0.f,0.f},{0.f,0.f,0.f,0.f}};
#pragma unroll
        for (int kb = 0; kb < 4; ++kb) {
            const int ko = kb * 32 + lg * 8;
            f16x8 b;
            b = as_f16x8(*(const u16x8*)&bp[(0 * 16 + l15) * PB_STRIDE + ko]);
            air[0] = __builtin_amdgcn_mfma_f32_16x16x32_f16(a_ag[0][kb], b, air[0], 0, 0, 0);
            air[1] = __builtin_amdgcn_mfma_f32_16x16x32_f16(a_ag[1][kb], b, air[1], 0, 0, 0);
            b = as_f16x8(*(const u16x8*)&bp[(1 * 16 + l15) * PB_STRIDE + ko]);
            aiz[0] = __builtin_amdgcn_mfma_f32_16x16x32_f16(a_ag[0][kb], b, aiz[0], 0, 0, 0);
            aiz[1] = __builtin_amdgcn_mfma_f32_16x16x32_f16(a_ag[1][kb], b, aiz[1], 0, 0, 0);
            b = as_f16x8(*(const u16x8*)&bp[(2 * 16 + l15) * PB_STRIDE + ko]);
            ain_[0] = __builtin_amdgcn_mfma_f32_16x16x32_f16(a_ag[0][kb], b, ain_[0], 0, 0, 0);
            ain_[1] = __builtin_amdgcn_mfma_f32_16x16x32_f16(a_ag[1][kb], b, ain_[1], 0, 0, 0);
            b = as_f16x8(*(const u16x8*)&bp[(3 * 16 + l15) * PB_STRIDE + ko]);
            ahr[0] = __builtin_amdgcn_mfma_f32_16x16x32_f16(a_h[0][kb], b, ahr[0], 0, 0, 0);
            ahr[1] = __builtin_amdgcn_mfma_f32_16x16x32_f16(a_h[1][kb], b, ahr[1], 0, 0, 0);
            b = as_f16x8(*(const u16x8*)&bp[(4 * 16 + l15) * PB_STRIDE + ko]);
            ahz[0] = __builtin_amdgcn_mfma_f32_16x16x32_f16(a_h[0][kb], b, ahz[0], 0, 0, 0);
            ahz[1] = __builtin_amdgcn_mfma_f32_16x16x32_f16(a_h[1][kb], b, ahz[1], 0, 0, 0);
            b = as_f16x8(*(const u16x8*)&bp[(5 * 16 + l15) * PB_STRIDE + ko]);
            ahn[0] = __builtin_amdgcn_mfma_f32_16x16x32_f16(a_h[0][kb], b, ahn[0], 0, 0, 0);
            ahn[1] = __builtin_amdgcn_mfma_f32_16x16x32_f16(a_h[1][kb], b, ahn[1], 0, 0, 0);
        }
#pragma unroll
        for (int m = 0; m < 2; ++m)
#pragma unroll
            for (int i = 0; i < 4; ++i) {
                const int n = rbase + m * 16 + lg * 4 + i;
                if (n < N) {
                    const float r  = sigm_(air[m][i] + bir + ahr[m][i] + bhr);
                    const float z  = sigm_(aiz[m][i] + biz + ahz[m][i] + bhz);
                    const float nn = tanh_(ain_[m][i] + bin + r * (ahn[m][i] + bhn));
                    h16[(size_t)n * D_NODE + d] = (_Float16)((1.f - z) * nn + z * hv[m][i]);
                }
            }
        if (nb < 7) write_panel((nb + 1) & 1);
        __syncthreads();
    }
}

// ---------------- launch ----------------
extern "C" void kernel_launch(void* const* d_in, const int* in_sizes, int n_in,
                              void* d_out, int out_size, void* d_ws, size_t ws_size,
                              hipStream_t stream) {
    const float* h0   = (const float*)d_in[0];
    const float* e    = (const float*)d_in[1];
    const int*   src  = (const int*)d_in[2];
    const int*   dst  = (const int*)d_in[3];
    const float* cond = (const float*)d_in[4];
    const float* UW   = (const float*)d_in[5];
    const float* Ub   = (const float*)d_in[6];
    const float* Wih  = (const float*)d_in[7];
    const float* Whh  = (const float*)d_in[8];
    const float* bih  = (const float*)d_in[9];
    const float* bhh  = (const float*)d_in[10];

    const int N = in_sizes[0] / D_NODE;
    const int E = in_sizes[2];
    const int NB = (N + 1023) / 1024;   // scan blocks (<= 256)
    const int NT = (N + ROWS_BLK - 1) / ROWS_BLK;

    char* wsb = (char*)d_ws;
    size_t off = 0;
    auto carve = [&](size_t bytes) -> char* {
        char* p = wsb + off;
        off = (off + bytes + 255) & ~(size_t)255;
        return p;
    };
    int*   cnt      = (int*)carve((size_t)N * 4);
    int*   row_ptr  = (int*)carve(((size_t)N + 1) * 4);
    int*   cursor   = (int*)carve((size_t)N * 4);
    int*   csr_src  = (int*)carve((size_t)E * 4);
    int*   csr_eid  = (int*)carve((size_t)E * 4);
    int*   blk_sums = (int*)carve(256 * 4);
    float* cvec     = (float*)carve(3 * D_NODE * 4);
    _Float16* S_e  = (_Float16*)carve((size_t)N * D_EDGE * 2);
    _Float16* S_h  = (_Float16*)carve((size_t)N * D_NODE * 2);
    _Float16* aggb = (_Float16*)carve((size_t)N * D_NODE * 2);
    _Float16* h16  = (_Float16*)carve((size_t)N * D_NODE * 2);
    _Float16* UWp  = (_Float16*)carve((size_t)3 * D_NODE * 320 * 2);
    _Float16* Wihh = (_Float16*)carve((size_t)3 * GRU3 * D_NODE * 2);
    _Float16* Whhh = (_Float16*)carve((size_t)3 * GRU3 * D_NODE * 2);
    const size_t e16_bytes = (size_t)E * D_EDGE * 2;
    _Float16* e16 = nullptr;
    if (off + e16_bytes + 256 <= ws_size) e16 = (_Float16*)carve(e16_bytes);
    (void)n_in; (void)out_size;

    hipMemsetAsync(cnt, 0, (size_t)N * 4, stream);
    hist_k<<<(E + 255) / 256, 256, 0, stream>>>(dst, cnt, E);
    scan1_k<<<NB, 256, 0, stream>>>(cnt, row_ptr, blk_sums, N);
    scan2_k<<<1, 256, 0, stream>>>(blk_sums, NB, row_ptr, N, E);
    scan3_k<<<NB, 256, 0, stream>>>(row_ptr, cursor, blk_sums, N);
    scatter_k<<<(E + 255) / 256, 256, 0, stream>>>(src, dst, cursor, csr_src, csr_eid, E);
    compute_c_k<<<1, 384, 0, stream>>>(UW, Ub, cond, cvec);
    cvt_uwp_k<<<3 * D_NODE, 320, 0, stream>>>(UW, UWp);
    {
        const int n1 = 3 * GRU3 * D_NODE;
        cvt_f32_k<<<(n1 + 255) / 256, 256, 0, stream>>>(Wih, Wihh, n1);
        cvt_f32_k<<<(n1 + 255) / 256, 256, 0, stream>>>(Whh, Whhh, n1);
    }
    {
        const int n4 = N * D_NODE / 4;
        cvt4_k<<<(n4 + 255) / 256, 256, 0, stream>>>(h0, h16, n4);   // seed fp16 mirror
    }
    if (e16) {
        const int n4 = E * D_EDGE / 4;
        cvt4_k<<<(n4 + 255) / 256, 256, 0, stream>>>(e, e16, n4);
        gather_e16_k<<<(N + 7) / 8, 256, 0, stream>>>(e16, row_ptr, csr_eid, S_e, N);
    } else {
        gather_e_k<<<(N + 3) / 4, 256, 0, stream>>>(e, row_ptr, csr_eid, S_e, N);
    }

    for (int k = 0; k < 3; ++k) {
        gather_h_k<<<(N + 7) / 8, 256, 0, stream>>>(h16, row_ptr, csr_src, S_h, N);
        agg_k<<<NT, 512, 0, stream>>>(
            h16, S_h, S_e, row_ptr, cvec + k * D_NODE,
            UWp + (size_t)k * D_NODE * 320, aggb, N);
        gru_k<<<NT, 512, 0, stream>>>(
            h16, aggb,
            Wihh + (size_t)k * GRU3 * D_NODE,
            Whhh + (size_t)k * GRU3 * D_NODE,
            bih + (size_t)k * GRU3,
            bhh + (size_t)k * GRU3,
            N);   // fp16-state only; in-place safe (block-local rows)
    }
    {
        const int n4 = N * D_NODE / 4;
        cvt_out_k<<<(n4 + 255) / 256, 256, 0, stream>>>(h16, (float*)d_out, n4);
    }
}

// Round 18
// 519.946 us; speedup vs baseline: 1.4868x; 1.0291x over previous
//
#include <hip/hip_runtime.h>
#include <hip/hip_bf16.h>
#include <hip/hip_fp16.h>

// GGM encode, decomposed (inputs fp32; internal fp16 MFMA, fp32 accum; output fp32):
//   agg[v] = deg(v)*(U1 h_v + c_k) + U2*S_h[v] + U3*S_e[v]
//   GRU: gi = agg@Wih^T + bih, gh = h@Whh^T + bhh, fused elementwise in fp32.
// R17->R18: gather ILP boost. 4 nodes/wave (16 lanes/node; h: 16B/lane uint4,
// e: 8B/lane uint2) -> 16 outstanding scattered row-loads/wave (2x R17), same
// bytes, same per-column accumulation order (bit-identical). MFMA kernels
// unchanged from the verified R14/R17 config.

#define D_NODE 128
#define D_EDGE 64
#define D_IN   322
#define GRU3   384
#define ROWS_BLK 256    // rows per (512-thread) MFMA block
#define PA_STRIDE 328   // panel-A row stride (elems): 656B
#define PB_STRIDE 136   // panel-B row stride (elems): 272B

typedef _Float16 f16x8 __attribute__((ext_vector_type(8)));
typedef _Float16 f16x4 __attribute__((ext_vector_type(4)));
typedef _Float16 f16x2 __attribute__((ext_vector_type(2)));
typedef float    f32x4 __attribute__((ext_vector_type(4)));
typedef unsigned short u16x8 __attribute__((ext_vector_type(8)));

__device__ __forceinline__ f16x8 as_f16x8(u16x8 v) { return __builtin_bit_cast(f16x8, v); }
__device__ __forceinline__ float sigm_(float x) { return 1.f / (1.f + __expf(-x)); }
__device__ __forceinline__ float tanh_(float x) { return 1.f - 2.f / (__expf(2.f * x) + 1.f); }

// ---------------- CSR build ----------------
__global__ void hist_k(const int* __restrict__ dst, int* __restrict__ cnt, int E) {
    int t = blockIdx.x * 256 + threadIdx.x;
    if (t < E) atomicAdd(&cnt[dst[t]], 1);
}

__global__ __launch_bounds__(256) void scan1_k(const int* __restrict__ cnt, int* __restrict__ row_ptr,
                                               int* __restrict__ blk_sums, int N) {
    __shared__ int s[256];
    const int t = threadIdx.x;
    const int base = blockIdx.x * 1024 + t * 4;
    int v0 = (base + 0 < N) ? cnt[base + 0] : 0;
    int v1 = (base + 1 < N) ? cnt[base + 1] : 0;
    int v2 = (base + 2 < N) ? cnt[base + 2] : 0;
    int v3 = (base + 3 < N) ? cnt[base + 3] : 0;
    const int tot = v0 + v1 + v2 + v3;
    s[t] = tot;
    __syncthreads();
    for (int off = 1; off < 256; off <<= 1) {
        int u = (t >= off) ? s[t - off] : 0;
        __syncthreads();
        s[t] += u;
        __syncthreads();
    }
    const int excl = s[t] - tot;
    if (base + 0 < N) row_ptr[base + 0] = excl;
    if (base + 1 < N) row_ptr[base + 1] = excl + v0;
    if (base + 2 < N) row_ptr[base + 2] = excl + v0 + v1;
    if (base + 3 < N) row_ptr[base + 3] = excl + v0 + v1 + v2;
    if (t == 255) blk_sums[blockIdx.x] = s[255];
}

__global__ __launch_bounds__(256) void scan2_k(int* __restrict__ blk_sums, int NB,
                                               int* __restrict__ row_ptr, int N, int E) {
    __shared__ int s[256];
    const int t = threadIdx.x;
    const int v = (t < NB) ? blk_sums[t] : 0;
    s[t] = v;
    __syncthreads();
    for (int off = 1; off < 256; off <<= 1) {
        int u = (t >= off) ? s[t - off] : 0;
        __syncthreads();
        s[t] += u;
        __syncthreads();
    }
    if (t < NB) blk_sums[t] = s[t] - v;
    if (t == 0) row_ptr[N] = E;
}

__global__ __launch_bounds__(256) void scan3_k(int* __restrict__ row_ptr, int* __restrict__ cursor,
                                               const int* __restrict__ blk_sums, int N) {
    const int off = blk_sums[blockIdx.x];
    const int base = blockIdx.x * 1024 + threadIdx.x * 4;
#pragma unroll
    for (int j = 0; j < 4; ++j) {
        const int i = base + j;
        if (i < N) {
            const int v = row_ptr[i] + off;
            row_ptr[i] = v;
            cursor[i] = v;
        }
    }
}

__global__ void scatter_k(const int* __restrict__ src, const int* __restrict__ dst,
                          int* __restrict__ cursor, int* __restrict__ csr_src,
                          int* __restrict__ csr_eid, int E) {
    int t = blockIdx.x * 256 + threadIdx.x;
    if (t < E) {
        int d = dst[t];
        int pos = atomicAdd(&cursor[d], 1);
        csr_src[pos] = src[t];
        csr_eid[pos] = t;
    }
}

// ---------------- converts ----------------
__global__ __launch_bounds__(320) void cvt_uwp_k(const float* __restrict__ in, _Float16* __restrict__ out) {
    const int row = blockIdx.x;   // 0..383
    const int t = threadIdx.x;    // 0..319
    out[(size_t)row * 320 + t] = (_Float16)in[(size_t)row * D_IN + t];
}

__global__ void cvt_f32_k(const float* __restrict__ in, _Float16* __restrict__ out, int n) {
    int t = blockIdx.x * 256 + threadIdx.x;
    if (t < n) out[t] = (_Float16)in[t];
}

__global__ void cvt4_k(const float* __restrict__ in, _Float16* __restrict__ out, int n4) {
    int t = blockIdx.x * 256 + threadIdx.x;
    if (t < n4) {
        const f32x4 v = ((const f32x4*)in)[t];
        f16x4 r;
        r[0] = (_Float16)v[0]; r[1] = (_Float16)v[1];
        r[2] = (_Float16)v[2]; r[3] = (_Float16)v[3];
        ((f16x4*)out)[t] = r;
    }
}

__global__ void cvt_out_k(const _Float16* __restrict__ in, float* __restrict__ out, int n4) {
    int t = blockIdx.x * 256 + threadIdx.x;
    if (t < n4) {
        const f16x4 v = ((const f16x4*)in)[t];
        f32x4 r;
        r[0] = (float)v[0]; r[1] = (float)v[1];
        r[2] = (float)v[2]; r[3] = (float)v[3];
        ((f32x4*)out)[t] = r;
    }
}

// ---------------- c_k = U4*cond + U_b (fp32 exact) ----------------
__global__ void compute_c_k(const float* __restrict__ UW, const float* __restrict__ Ub,
                            const float* __restrict__ cond, float* __restrict__ cvec) {
    int t = threadIdx.x;
    if (t < 3 * D_NODE) {
        int k = t >> 7, i = t & 127;
        const float* u = UW + (size_t)k * D_NODE * D_IN + (size_t)i * D_IN + 320;
        cvec[t] = u[0] * cond[0] + u[1] * cond[1] + Ub[k * D_NODE + i];
    }
}

// ---------------- segment sums: 4 nodes/wave (16 lanes per node) ----------------
__global__ __launch_bounds__(256) void gather_e_k(const float* __restrict__ e,
                                                  const int* __restrict__ row_ptr,
                                                  const int* __restrict__ csr_eid,
                                                  _Float16* __restrict__ S_e, int N) {
    const int wave = threadIdx.x >> 6, lane = threadIdx.x & 63;
    const int n = blockIdx.x * 4 + wave;
    if (n >= N) return;
    const int p0 = row_ptr[n], p1 = row_ptr[n + 1];
    float a = 0.f, b = 0.f, c = 0.f, d = 0.f;
    int p = p0;
    for (; p + 3 < p1; p += 4) {
        const int e0 = csr_eid[p], e1 = csr_eid[p + 1], e2 = csr_eid[p + 2], e3 = csr_eid[p + 3];
        a += e[(size_t)e0 * D_EDGE + lane];
        b += e[(size_t)e1 * D_EDGE + lane];
        c += e[(size_t)e2 * D_EDGE + lane];
        d += e[(size_t)e3 * D_EDGE + lane];
    }
    for (; p < p1; ++p) a += e[(size_t)csr_eid[p] * D_EDGE + lane];
    S_e[(size_t)n * D_EDGE + lane] = (_Float16)((a + b) + (c + d));
}

// fp16-e: 128B rows, 16 lanes/node, uint2 (4 cols f16) per lane; 4 nodes/wave.
__global__ __launch_bounds__(256) void gather_e16_k(const _Float16* __restrict__ e16,
                                                    const int* __restrict__ row_ptr,
                                                    const int* __restrict__ csr_eid,
                                                    _Float16* __restrict__ S_e, int N) {
    const int wave = threadIdx.x >> 6, lane = threadIdx.x & 63;
    const int q = lane >> 4, ln = lane & 15;
    const int n = blockIdx.x * 16 + wave * 4 + q;
    if (n >= N) return;
    const uint2* ep = (const uint2*)e16;   // 16 uint2 per row
    const int p0 = row_ptr[n], p1 = row_ptr[n + 1];
    float aA[4] = {0.f,0.f,0.f,0.f}, aB[4] = {0.f,0.f,0.f,0.f};
    float aC[4] = {0.f,0.f,0.f,0.f}, aD[4] = {0.f,0.f,0.f,0.f};
    int p = p0;
    for (; p + 3 < p1; p += 4) {
        const int e0 = csr_eid[p], e1 = csr_eid[p + 1], e2 = csr_eid[p + 2], e3 = csr_eid[p + 3];
        const f16x4 v0 = __builtin_bit_cast(f16x4, ep[(size_t)e0 * 16 + ln]);
        const f16x4 v1 = __builtin_bit_cast(f16x4, ep[(size_t)e1 * 16 + ln]);
        const f16x4 v2 = __builtin_bit_cast(f16x4, ep[(size_t)e2 * 16 + ln]);
        const f16x4 v3 = __builtin_bit_cast(f16x4, ep[(size_t)e3 * 16 + ln]);
#pragma unroll
        for (int j = 0; j < 4; ++j) {
            aA[j] += (float)v0[j]; aB[j] += (float)v1[j];
            aC[j] += (float)v2[j]; aD[j] += (float)v3[j];
        }
    }
    for (; p < p1; ++p) {
        const f16x4 v = __builtin_bit_cast(f16x4, ep[(size_t)csr_eid[p] * 16 + ln]);
#pragma unroll
        for (int j = 0; j < 4; ++j) aA[j] += (float)v[j];
    }
    f16x4 r;
#pragma unroll
    for (int j = 0; j < 4; ++j) r[j] = (_Float16)((aA[j] + aB[j]) + (aC[j] + aD[j]));
    ((uint2*)S_e)[(size_t)n * 16 + ln] = __builtin_bit_cast(uint2, r);
}

// fp16 h rows: 256B/row, 16 lanes/node, uint4 (8 cols f16) per lane; 4 nodes/wave.
__global__ __launch_bounds__(256) void gather_h_k(const _Float16* __restrict__ h16,
                                                  const int* __restrict__ row_ptr,
                                                  const int* __restrict__ csr_src,
                                                  _Float16* __restrict__ S_h, int N) {
    const int wave = threadIdx.x >> 6, lane = threadIdx.x & 63;
    const int q = lane >> 4, ln = lane & 15;
    const int n = blockIdx.x * 16 + wave * 4 + q;
    if (n >= N) return;
    const uint4* hp = (const uint4*)h16;   // 16 uint4 per row
    const int p0 = row_ptr[n], p1 = row_ptr[n + 1];
    float aA[8] = {0,0,0,0,0,0,0,0}, aB[8] = {0,0,0,0,0,0,0,0};
    float aC[8] = {0,0,0,0,0,0,0,0}, aD[8] = {0,0,0,0,0,0,0,0};
    int p = p0;
    for (; p + 3 < p1; p += 4) {
        const int s0 = csr_src[p], s1 = csr_src[p + 1], s2 = csr_src[p + 2], s3 = csr_src[p + 3];
        const f16x8 v0 = __builtin_bit_cast(f16x8, hp[(size_t)s0 * 16 + ln]);
        const f16x8 v1 = __builtin_bit_cast(f16x8, hp[(size_t)s1 * 16 + ln]);
        const f16x8 v2 = __builtin_bit_cast(f16x8, hp[(size_t)s2 * 16 + ln]);
        const f16x8 v3 = __builtin_bit_cast(f16x8, hp[(size_t)s3 * 16 + ln]);
#pragma unroll
        for (int j = 0; j < 8; ++j) {
            aA[j] += (float)v0[j]; aB[j] += (float)v1[j];
            aC[j] += (float)v2[j]; aD[j] += (float)v3[j];
        }
    }
    for (; p < p1; ++p) {
        const f16x8 v = __builtin_bit_cast(f16x8, hp[(size_t)csr_src[p] * 16 + ln]);
#pragma unroll
        for (int j = 0; j < 8; ++j) aA[j] += (float)v[j];
    }
    f16x8 r;
#pragma unroll
    for (int j = 0; j < 8; ++j) r[j] = (_Float16)((aA[j] + aB[j]) + (aC[j] + aD[j]));
    ((uint4*)S_h)[(size_t)n * 16 + ln] = __builtin_bit_cast(uint4, r);
}

// ---------------- agg kernel (512 thr, 8 waves, 256 rows/block) ----------------
__global__ __launch_bounds__(512, 2) void agg_k(
    const _Float16* __restrict__ h16,
    const _Float16* __restrict__ S_h,
    const _Float16* __restrict__ S_e,
    const int* __restrict__ row_ptr,
    const float* __restrict__ cvec,
    const _Float16* __restrict__ UWp,   // [128][320] fp16, this round's slice
    _Float16* __restrict__ agg,
    int N) {
    __shared__ __align__(16) _Float16 pbuf[2][16 * PA_STRIDE];  // 2 x 10.5 KB

    const int tid  = threadIdx.x;
    const int wave = tid >> 6;
    const int lane = tid & 63;
    const int l15  = lane & 15;
    const int lg   = lane >> 4;
    const int rbase = blockIdx.x * ROWS_BLK + wave * 32;

    const unsigned short* hp  = (const unsigned short*)h16;
    const unsigned short* shp = (const unsigned short*)S_h;
    const unsigned short* sep = (const unsigned short*)S_e;
    const unsigned short* uwp = (const unsigned short*)UWp;

    f16x8 a_h[2][4], a_sh[2][4], a_se[2][2];
#pragma unroll
    for (int m = 0; m < 2; ++m) {
        const int arow = min(rbase + m * 16 + l15, N - 1);
#pragma unroll
        for (int kb = 0; kb < 4; ++kb) {
            a_h[m][kb]  = as_f16x8(*(const u16x8*)(hp  + (size_t)arow * D_NODE + kb * 32 + lg * 8));
            a_sh[m][kb] = as_f16x8(*(const u16x8*)(shp + (size_t)arow * D_NODE + kb * 32 + lg * 8));
        }
#pragma unroll
        for (int kb = 0; kb < 2; ++kb)
            a_se[m][kb] = as_f16x8(*(const u16x8*)(sep + (size_t)arow * D_EDGE + kb * 32 + lg * 8));
    }
    float degv[2][4];
#pragma unroll
    for (int m = 0; m < 2; ++m)
#pragma unroll
        for (int i = 0; i < 4; ++i) {
            const int n = min(rbase + m * 16 + lg * 4 + i, N - 1);
            degv[m][i] = (float)(row_ptr[n + 1] - row_ptr[n]);
        }

    // panel staging: 640 16B-chunks; 512 threads -> chunk tid (all) + 512+tid (tid<128)
    u16x8 pr0, pr1;
    auto load_panel = [&](int nb) {
        const int c0 = tid, c1 = 512 + tid;
        pr0 = *(const u16x8*)(uwp + (size_t)(nb * 16 + c0 / 40) * 320 + (c0 % 40) * 8);
        if (c1 < 640)
            pr1 = *(const u16x8*)(uwp + (size_t)(nb * 16 + c1 / 40) * 320 + (c1 % 40) * 8);
    };
    auto write_panel = [&](int b) {
        const int c0 = tid, c1 = 512 + tid;
        *(u16x8*)&pbuf[b][(c0 / 40) * PA_STRIDE + (c0 % 40) * 8] = pr0;
        if (c1 < 640)
            *(u16x8*)&pbuf[b][(c1 / 40) * PA_STRIDE + (c1 % 40) * 8] = pr1;
    };

    load_panel(0);
    write_panel(0);
    __syncthreads();

#pragma unroll 1
    for (int nb = 0; nb < 8; ++nb) {
        if (nb < 7) load_panel(nb + 1);
        const _Float16* bp = pbuf[nb & 1];
        f32x4 acc1[2] = {{0.f,0.f,0.f,0.f},{0.f,0.f,0.f,0.f}};
        f32x4 acc2[2] = {{0.f,0.f,0.f,0.f},{0.f,0.f,0.f,0.f}};
#pragma unroll
        for (int kb = 0; kb < 10; ++kb) {
            f16x8 b = as_f16x8(*(const u16x8*)&bp[l15 * PA_STRIDE + kb * 32 + lg * 8]);
            if (kb < 4) {
                acc1[0] = __builtin_amdgcn_mfma_f32_16x16x32_f16(a_h[0][kb], b, acc1[0], 0, 0, 0);
                acc1[1] = __builtin_amdgcn_mfma_f32_16x16x32_f16(a_h[1][kb], b, acc1[1], 0, 0, 0);
            } else if (kb < 8) {
                acc2[0] = __builtin_amdgcn_mfma_f32_16x16x32_f16(a_sh[0][kb-4], b, acc2[0], 0, 0, 0);
                acc2[1] = __builtin_amdgcn_mfma_f32_16x16x32_f16(a_sh[1][kb-4], b, acc2[1], 0, 0, 0);
            } else {
                acc2[0] = __builtin_amdgcn_mfma_f32_16x16x32_f16(a_se[0][kb-8], b, acc2[0], 0, 0, 0);
                acc2[1] = __builtin_amdgcn_mfma_f32_16x16x32_f16(a_se[1][kb-8], b, acc2[1], 0, 0, 0);
            }
        }
        const float cv = cvec[nb * 16 + l15];
#pragma unroll
        for (int m = 0; m < 2; ++m)
#pragma unroll
            for (int i = 0; i < 4; ++i) {
                const int n = rbase + m * 16 + lg * 4 + i;
                if (n < N)
                    agg[(size_t)n * D_NODE + nb * 16 + l15] =
                        (_Float16)(degv[m][i] * (acc1[m][i] + cv) + acc2[m][i]);
            }
        if (nb < 7) write_panel((nb + 1) & 1);
        __syncthreads();
    }
}

// ---------------- GRU kernel (512 thr, 8 waves, 256 rows/block; fp16-state) ----------------
__global__ __launch_bounds__(512, 2) void gru_k(
    _Float16* __restrict__ h16,          // read frags + hv; write fp16(h') in-place
    const _Float16* __restrict__ agg,
    const _Float16* __restrict__ Wihh,  // [384][128] fp16
    const _Float16* __restrict__ Whhh,  // [384][128] fp16
    const float* __restrict__ bih,
    const float* __restrict__ bhh,
    int N) {
    __shared__ __align__(16) _Float16 pbuf[2][96 * PB_STRIDE];  // 2 x 25.5 KB

    const int tid  = threadIdx.x;
    const int wave = tid >> 6;
    const int lane = tid & 63;
    const int l15  = lane & 15;
    const int lg   = lane >> 4;
    const int rbase = blockIdx.x * ROWS_BLK + wave * 32;

    const unsigned short* hp  = (const unsigned short*)h16;
    const unsigned short* agp = (const unsigned short*)agg;
    const unsigned short* wih = (const unsigned short*)Wihh;
    const unsigned short* whh = (const unsigned short*)Whhh;

    f16x8 a_ag[2][4], a_h[2][4];
#pragma unroll
    for (int m = 0; m < 2; ++m) {
        const int arow = min(rbase + m * 16 + l15, N - 1);
#pragma unroll
        for (int kb = 0; kb < 4; ++kb) {
            a_ag[m][kb] = as_f16x8(*(const u16x8*)(agp + (size_t)arow * D_NODE + kb * 32 + lg * 8));
            a_h[m][kb]  = as_f16x8(*(const u16x8*)(hp  + (size_t)arow * D_NODE + kb * 32 + lg * 8));
        }
    }

    // panel staging: 1536 16B-chunks = 3 rounds x 512 thr (exact)
    u16x8 pr[3];
    auto load_panel = [&](int nb) {
#pragma unroll
        for (int r = 0; r < 3; ++r) {
            const int c = r * 512 + tid;
            const int row = c >> 4;            // 0..95
            const int off = (c & 15) * 8;      // elems
            const int gate = row >> 4;         // 0..5
            const int col = nb * 16 + (row & 15) + (gate % 3) * D_NODE;
            const unsigned short* mat = (gate < 3) ? wih : whh;
            pr[r] = *(const u16x8*)(mat + (size_t)col * D_NODE + off);
        }
    };
    auto write_panel = [&](int b) {
#pragma unroll
        for (int r = 0; r < 3; ++r) {
            const int c = r * 512 + tid;
            const int row = c >> 4;
            const int off = (c & 15) * 8;
            *(u16x8*)&pbuf[b][row * PB_STRIDE + off] = pr[r];
        }
    };

    load_panel(0);
    write_panel(0);
    __syncthreads();

#pragma unroll 1
    for (int nb = 0; nb < 8; ++nb) {
        if (nb < 7) load_panel(nb + 1);
        const int d = nb * 16 + l15;
        float hv[2][4];
#pragma unroll
        for (int m = 0; m < 2; ++m)
#pragma unroll
            for (int i = 0; i < 4; ++i) {
                const int n = min(rbase + m * 16 + lg * 4 + i, N - 1);
                hv[m][i] = (float)h16[(size_t)n * D_NODE + d];
            }
        const float bir = bih[d],       biz = bih[128 + d], bin = bih[256 + d];
        const float bhr = bhh[d],       bhz = bhh[128 + d], bhn = bhh[256 + d];

        const _Float16* bp = pbuf[nb & 1];
        f32x4 air[2] = {{0.f,0.f,0.f,0.f},{0.f,0.f,0.f,0.f}};
        f32x4 aiz[2] = {{0.f,0.f,0.f,0.f},{0.f,0.f,0.f,0.f}};
        f32x4 ain_[2] = {{0.f,0.f,0.f,0.f},{0.f,0.f,0.f,0.f}};
        f32x4 ahr[2] = {{0.f,0.f,0.f,0.f},{0.f,0.f,0.f,0.f}};
        f32x4 ahz[2] = {{0.f,0.f,0.f,0.f},{0.f,0.f,0.f,0.f}};
        f32x4 ahn[2] = {{0.f,0.f,0.f,0.f},{0.f,0.f,0.f,0.f}};
#pragma unroll
        for (int kb = 0; kb < 4; ++kb) {
            const int ko = kb * 32 + lg * 8;
            f16x8 b;
            b = as_f16x8(*(const u16x8*)&bp[(0 * 16 + l15) * PB_STRIDE + ko]);
            air[0] = __builtin_amdgcn_mfma_f32_16x16x32_f16(a_ag[0][kb], b, air[0], 0, 0, 0);
            air[1] = __builtin_amdgcn_mfma_f32_16x16x32_f16(a_ag[1][kb], b, air[1], 0, 0, 0);
            b = as_f16x8(*(const u16x8*)&bp[(1 * 16 + l15) * PB_STRIDE + ko]);
            aiz[0] = __builtin_amdgcn_mfma_f32_16x16x32_f16(a_ag[0][kb], b, aiz[0], 0, 0, 0);
            aiz[1] = __builtin_amdgcn_mfma_f32_16x16x32_f16(a_ag[1][kb], b, aiz[1], 0, 0, 0);
            b = as_f16x8(*(const u16x8*)&bp[(2 * 16 + l15) * PB_STRIDE + ko]);
            ain_[0] = __builtin_amdgcn_mfma_f32_16x16x32_f16(a_ag[0][kb], b, ain_[0], 0, 0, 0);
            ain_[1] = __builtin_amdgcn_mfma_f32_16x16x32_f16(a_ag[1][kb], b, ain_[1], 0, 0, 0);
            b = as_f16x8(*(const u16x8*)&bp[(3 * 16 + l15) * PB_STRIDE + ko]);
            ahr[0] = __builtin_amdgcn_mfma_f32_16x16x32_f16(a_h[0][kb], b, ahr[0], 0, 0, 0);
            ahr[1] = __builtin_amdgcn_mfma_f32_16x16x32_f16(a_h[1][kb], b, ahr[1], 0, 0, 0);
            b = as_f16x8(*(const u16x8*)&bp[(4 * 16 + l15) * PB_STRIDE + ko]);
            ahz[0] = __builtin_amdgcn_mfma_f32_16x16x32_f16(a_h[0][kb], b, ahz[0], 0, 0, 0);
            ahz[1] = __builtin_amdgcn_mfma_f32_16x16x32_f16(a_h[1][kb], b, ahz[1], 0, 0, 0);
            b = as_f16x8(*(const u16x8*)&bp[(5 * 16 + l15) * PB_STRIDE + ko]);
            ahn[0] = __builtin_amdgcn_mfma_f32_16x16x32_f16(a_h[0][kb], b, ahn[0], 0, 0, 0);
            ahn[1] = __builtin_amdgcn_mfma_f32_16x16x32_f16(a_h[1][kb], b, ahn[1], 0, 0, 0);
        }
#pragma unroll
        for (int m = 0; m < 2; ++m)
#pragma unroll
            for (int i = 0; i < 4; ++i) {
                const int n = rbase + m * 16 + lg * 4 + i;
                if (n < N) {
                    const float r  = sigm_(air[m][i] + bir + ahr[m][i] + bhr);
                    const float z  = sigm_(aiz[m][i] + biz + ahz[m][i] + bhz);
                    const float nn = tanh_(ain_[m][i] + bin + r * (ahn[m][i] + bhn));
                    h16[(size_t)n * D_NODE + d] = (_Float16)((1.f - z) * nn + z * hv[m][i]);
                }
            }
        if (nb < 7) write_panel((nb + 1) & 1);
        __syncthreads();
    }
}

// ---------------- launch ----------------
extern "C" void kernel_launch(void* const* d_in, const int* in_sizes, int n_in,
                              void* d_out, int out_size, void* d_ws, size_t ws_size,
                              hipStream_t stream) {
    const float* h0   = (const float*)d_in[0];
    const float* e    = (const float*)d_in[1];
    const int*   src  = (const int*)d_in[2];
    const int*   dst  = (const int*)d_in[3];
    const float* cond = (const float*)d_in[4];
    const float* UW   = (const float*)d_in[5];
    const float* Ub   = (const float*)d_in[6];
    const float* Wih  = (const float*)d_in[7];
    const float* Whh  = (const float*)d_in[8];
    const float* bih  = (const float*)d_in[9];
    const float* bhh  = (const float*)d_in[10];

    const int N = in_sizes[0] / D_NODE;
    const int E = in_sizes[2];
    const int NB = (N + 1023) / 1024;   // scan blocks (<= 256)
    const int NT = (N + ROWS_BLK - 1) / ROWS_BLK;

    char* wsb = (char*)d_ws;
    size_t off = 0;
    auto carve = [&](size_t bytes) -> char* {
        char* p = wsb + off;
        off = (off + bytes + 255) & ~(size_t)255;
        return p;
    };
    int*   cnt      = (int*)carve((size_t)N * 4);
    int*   row_ptr  = (int*)carve(((size_t)N + 1) * 4);
    int*   cursor   = (int*)carve((size_t)N * 4);
    int*   csr_src  = (int*)carve((size_t)E * 4);
    int*   csr_eid  = (int*)carve((size_t)E * 4);
    int*   blk_sums = (int*)carve(256 * 4);
    float* cvec     = (float*)carve(3 * D_NODE * 4);
    _Float16* S_e  = (_Float16*)carve((size_t)N * D_EDGE * 2);
    _Float16* S_h  = (_Float16*)carve((size_t)N * D_NODE * 2);
    _Float16* aggb = (_Float16*)carve((size_t)N * D_NODE * 2);
    _Float16* h16  = (_Float16*)carve((size_t)N * D_NODE * 2);
    _Float16* UWp  = (_Float16*)carve((size_t)3 * D_NODE * 320 * 2);
    _Float16* Wihh = (_Float16*)carve((size_t)3 * GRU3 * D_NODE * 2);
    _Float16* Whhh = (_Float16*)carve((size_t)3 * GRU3 * D_NODE * 2);
    const size_t e16_bytes = (size_t)E * D_EDGE * 2;
    _Float16* e16 = nullptr;
    if (off + e16_bytes + 256 <= ws_size) e16 = (_Float16*)carve(e16_bytes);
    (void)n_in; (void)out_size;

    hipMemsetAsync(cnt, 0, (size_t)N * 4, stream);
    hist_k<<<(E + 255) / 256, 256, 0, stream>>>(dst, cnt, E);
    scan1_k<<<NB, 256, 0, stream>>>(cnt, row_ptr, blk_sums, N);
    scan2_k<<<1, 256, 0, stream>>>(blk_sums, NB, row_ptr, N, E);
    scan3_k<<<NB, 256, 0, stream>>>(row_ptr, cursor, blk_sums, N);
    scatter_k<<<(E + 255) / 256, 256, 0, stream>>>(src, dst, cursor, csr_src, csr_eid, E);
    compute_c_k<<<1, 384, 0, stream>>>(UW, Ub, cond, cvec);
    cvt_uwp_k<<<3 * D_NODE, 320, 0, stream>>>(UW, UWp);
    {
        const int n1 = 3 * GRU3 * D_NODE;
        cvt_f32_k<<<(n1 + 255) / 256, 256, 0, stream>>>(Wih, Wihh, n1);
        cvt_f32_k<<<(n1 + 255) / 256, 256, 0, stream>>>(Whh, Whhh, n1);
    }
    {
        const int n4 = N * D_NODE / 4;
        cvt4_k<<<(n4 + 255) / 256, 256, 0, stream>>>(h0, h16, n4);   // seed fp16 mirror
    }
    if (e16) {
        const int n4 = E * D_EDGE / 4;
        cvt4_k<<<(n4 + 255) / 256, 256, 0, stream>>>(e, e16, n4);
        gather_e16_k<<<(N + 15) / 16, 256, 0, stream>>>(e16, row_ptr, csr_eid, S_e, N);
    } else {
        gather_e_k<<<(N + 3) / 4, 256, 0, stream>>>(e, row_ptr, csr_eid, S_e, N);
    }

    for (int k = 0; k < 3; ++k) {
        gather_h_k<<<(N + 15) / 16, 256, 0, stream>>>(h16, row_ptr, csr_src, S_h, N);
        agg_k<<<NT, 512, 0, stream>>>(
            h16, S_h, S_e, row_ptr, cvec + k * D_NODE,
            UWp + (size_t)k * D_NODE * 320, aggb, N);
        gru_k<<<NT, 512, 0, stream>>>(
            h16, aggb,
            Wihh + (size_t)k * GRU3 * D_NODE,
            Whhh + (size_t)k * GRU3 * D_NODE,
            bih + (size_t)k * GRU3,
            bhh + (size_t)k * GRU3,
            N);   // fp16-state only; in-place safe (block-local rows)
    }
    {
        const int n4 = N * D_NODE / 4;
        cvt_out_k<<<(n4 + 255) / 256, 256, 0, stream>>>(h16, (float*)d_out, n4);
    }
}

// Round 19
// 506.255 us; speedup vs baseline: 1.5270x; 1.0270x over previous
//
#include <hip/hip_runtime.h>
#include <hip/hip_bf16.h>
#include <hip/hip_fp16.h>

// GGM encode, decomposed (inputs fp32; internal fp16 MFMA, fp32 accum; output fp32):
//   agg[v] = deg(v)*(U1 h_v + c_k) + U2*S_h[v] + U3*S_e[v]
//   GRU: gi = agg@Wih^T + bih, gh = h@Whh^T + bhh, fused elementwise in fp32.
// R18->R19: fold fp32 output into the LAST gru dispatch (separate clone gru_out_k,
// so rounds 0/1 keep the proven VGPR=112 codegen); delete cvt_out_k (77MB stream).
// Everything else identical to R18 (best: 520us).

#define D_NODE 128
#define D_EDGE 64
#define D_IN   322
#define GRU3   384
#define ROWS_BLK 256    // rows per (512-thread) MFMA block
#define PA_STRIDE 328   // panel-A row stride (elems): 656B
#define PB_STRIDE 136   // panel-B row stride (elems): 272B

typedef _Float16 f16x8 __attribute__((ext_vector_type(8)));
typedef _Float16 f16x4 __attribute__((ext_vector_type(4)));
typedef _Float16 f16x2 __attribute__((ext_vector_type(2)));
typedef float    f32x4 __attribute__((ext_vector_type(4)));
typedef unsigned short u16x8 __attribute__((ext_vector_type(8)));

__device__ __forceinline__ f16x8 as_f16x8(u16x8 v) { return __builtin_bit_cast(f16x8, v); }
__device__ __forceinline__ float sigm_(float x) { return 1.f / (1.f + __expf(-x)); }
__device__ __forceinline__ float tanh_(float x) { return 1.f - 2.f / (__expf(2.f * x) + 1.f); }

// ---------------- CSR build ----------------
__global__ void hist_k(const int* __restrict__ dst, int* __restrict__ cnt, int E) {
    int t = blockIdx.x * 256 + threadIdx.x;
    if (t < E) atomicAdd(&cnt[dst[t]], 1);
}

__global__ __launch_bounds__(256) void scan1_k(const int* __restrict__ cnt, int* __restrict__ row_ptr,
                                               int* __restrict__ blk_sums, int N) {
    __shared__ int s[256];
    const int t = threadIdx.x;
    const int base = blockIdx.x * 1024 + t * 4;
    int v0 = (base + 0 < N) ? cnt[base + 0] : 0;
    int v1 = (base + 1 < N) ? cnt[base + 1] : 0;
    int v2 = (base + 2 < N) ? cnt[base + 2] : 0;
    int v3 = (base + 3 < N) ? cnt[base + 3] : 0;
    const int tot = v0 + v1 + v2 + v3;
    s[t] = tot;
    __syncthreads();
    for (int off = 1; off < 256; off <<= 1) {
        int u = (t >= off) ? s[t - off] : 0;
        __syncthreads();
        s[t] += u;
        __syncthreads();
    }
    const int excl = s[t] - tot;
    if (base + 0 < N) row_ptr[base + 0] = excl;
    if (base + 1 < N) row_ptr[base + 1] = excl + v0;
    if (base + 2 < N) row_ptr[base + 2] = excl + v0 + v1;
    if (base + 3 < N) row_ptr[base + 3] = excl + v0 + v1 + v2;
    if (t == 255) blk_sums[blockIdx.x] = s[255];
}

__global__ __launch_bounds__(256) void scan2_k(int* __restrict__ blk_sums, int NB,
                                               int* __restrict__ row_ptr, int N, int E) {
    __shared__ int s[256];
    const int t = threadIdx.x;
    const int v = (t < NB) ? blk_sums[t] : 0;
    s[t] = v;
    __syncthreads();
    for (int off = 1; off < 256; off <<= 1) {
        int u = (t >= off) ? s[t - off] : 0;
        __syncthreads();
        s[t] += u;
        __syncthreads();
    }
    if (t < NB) blk_sums[t] = s[t] - v;
    if (t == 0) row_ptr[N] = E;
}

__global__ __launch_bounds__(256) void scan3_k(int* __restrict__ row_ptr, int* __restrict__ cursor,
                                               const int* __restrict__ blk_sums, int N) {
    const int off = blk_sums[blockIdx.x];
    const int base = blockIdx.x * 1024 + threadIdx.x * 4;
#pragma unroll
    for (int j = 0; j < 4; ++j) {
        const int i = base + j;
        if (i < N) {
            const int v = row_ptr[i] + off;
            row_ptr[i] = v;
            cursor[i] = v;
        }
    }
}

__global__ void scatter_k(const int* __restrict__ src, const int* __restrict__ dst,
                          int* __restrict__ cursor, int* __restrict__ csr_src,
                          int* __restrict__ csr_eid, int E) {
    int t = blockIdx.x * 256 + threadIdx.x;
    if (t < E) {
        int d = dst[t];
        int pos = atomicAdd(&cursor[d], 1);
        csr_src[pos] = src[t];
        csr_eid[pos] = t;
    }
}

// ---------------- converts ----------------
__global__ __launch_bounds__(320) void cvt_uwp_k(const float* __restrict__ in, _Float16* __restrict__ out) {
    const int row = blockIdx.x;   // 0..383
    const int t = threadIdx.x;    // 0..319
    out[(size_t)row * 320 + t] = (_Float16)in[(size_t)row * D_IN + t];
}

__global__ void cvt_f32_k(const float* __restrict__ in, _Float16* __restrict__ out, int n) {
    int t = blockIdx.x * 256 + threadIdx.x;
    if (t < n) out[t] = (_Float16)in[t];
}

__global__ void cvt4_k(const float* __restrict__ in, _Float16* __restrict__ out, int n4) {
    int t = blockIdx.x * 256 + threadIdx.x;
    if (t < n4) {
        const f32x4 v = ((const f32x4*)in)[t];
        f16x4 r;
        r[0] = (_Float16)v[0]; r[1] = (_Float16)v[1];
        r[2] = (_Float16)v[2]; r[3] = (_Float16)v[3];
        ((f16x4*)out)[t] = r;
    }
}

// ---------------- c_k = U4*cond + U_b (fp32 exact) ----------------
__global__ void compute_c_k(const float* __restrict__ UW, const float* __restrict__ Ub,
                            const float* __restrict__ cond, float* __restrict__ cvec) {
    int t = threadIdx.x;
    if (t < 3 * D_NODE) {
        int k = t >> 7, i = t & 127;
        const float* u = UW + (size_t)k * D_NODE * D_IN + (size_t)i * D_IN + 320;
        cvec[t] = u[0] * cond[0] + u[1] * cond[1] + Ub[k * D_NODE + i];
    }
}

// ---------------- segment sums: 4 nodes/wave (16 lanes per node) ----------------
__global__ __launch_bounds__(256) void gather_e_k(const float* __restrict__ e,
                                                  const int* __restrict__ row_ptr,
                                                  const int* __restrict__ csr_eid,
                                                  _Float16* __restrict__ S_e, int N) {
    const int wave = threadIdx.x >> 6, lane = threadIdx.x & 63;
    const int n = blockIdx.x * 4 + wave;
    if (n >= N) return;
    const int p0 = row_ptr[n], p1 = row_ptr[n + 1];
    float a = 0.f, b = 0.f, c = 0.f, d = 0.f;
    int p = p0;
    for (; p + 3 < p1; p += 4) {
        const int e0 = csr_eid[p], e1 = csr_eid[p + 1], e2 = csr_eid[p + 2], e3 = csr_eid[p + 3];
        a += e[(size_t)e0 * D_EDGE + lane];
        b += e[(size_t)e1 * D_EDGE + lane];
        c += e[(size_t)e2 * D_EDGE + lane];
        d += e[(size_t)e3 * D_EDGE + lane];
    }
    for (; p < p1; ++p) a += e[(size_t)csr_eid[p] * D_EDGE + lane];
    S_e[(size_t)n * D_EDGE + lane] = (_Float16)((a + b) + (c + d));
}

// fp16-e: 128B rows, 16 lanes/node, uint2 (4 cols f16) per lane; 4 nodes/wave.
__global__ __launch_bounds__(256) void gather_e16_k(const _Float16* __restrict__ e16,
                                                    const int* __restrict__ row_ptr,
                                                    const int* __restrict__ csr_eid,
                                                    _Float16* __restrict__ S_e, int N) {
    const int wave = threadIdx.x >> 6, lane = threadIdx.x & 63;
    const int q = lane >> 4, ln = lane & 15;
    const int n = blockIdx.x * 16 + wave * 4 + q;
    if (n >= N) return;
    const uint2* ep = (const uint2*)e16;   // 16 uint2 per row
    const int p0 = row_ptr[n], p1 = row_ptr[n + 1];
    float aA[4] = {0.f,0.f,0.f,0.f}, aB[4] = {0.f,0.f,0.f,0.f};
    float aC[4] = {0.f,0.f,0.f,0.f}, aD[4] = {0.f,0.f,0.f,0.f};
    int p = p0;
    for (; p + 3 < p1; p += 4) {
        const int e0 = csr_eid[p], e1 = csr_eid[p + 1], e2 = csr_eid[p + 2], e3 = csr_eid[p + 3];
        const f16x4 v0 = __builtin_bit_cast(f16x4, ep[(size_t)e0 * 16 + ln]);
        const f16x4 v1 = __builtin_bit_cast(f16x4, ep[(size_t)e1 * 16 + ln]);
        const f16x4 v2 = __builtin_bit_cast(f16x4, ep[(size_t)e2 * 16 + ln]);
        const f16x4 v3 = __builtin_bit_cast(f16x4, ep[(size_t)e3 * 16 + ln]);
#pragma unroll
        for (int j = 0; j < 4; ++j) {
            aA[j] += (float)v0[j]; aB[j] += (float)v1[j];
            aC[j] += (float)v2[j]; aD[j] += (float)v3[j];
        }
    }
    for (; p < p1; ++p) {
        const f16x4 v = __builtin_bit_cast(f16x4, ep[(size_t)csr_eid[p] * 16 + ln]);
#pragma unroll
        for (int j = 0; j < 4; ++j) aA[j] += (float)v[j];
    }
    f16x4 r;
#pragma unroll
    for (int j = 0; j < 4; ++j) r[j] = (_Float16)((aA[j] + aB[j]) + (aC[j] + aD[j]));
    ((uint2*)S_e)[(size_t)n * 16 + ln] = __builtin_bit_cast(uint2, r);
}

// fp16 h rows: 256B/row, 16 lanes/node, uint4 (8 cols f16) per lane; 4 nodes/wave.
__global__ __launch_bounds__(256) void gather_h_k(const _Float16* __restrict__ h16,
                                                  const int* __restrict__ row_ptr,
                                                  const int* __restrict__ csr_src,
                                                  _Float16* __restrict__ S_h, int N) {
    const int wave = threadIdx.x >> 6, lane = threadIdx.x & 63;
    const int q = lane >> 4, ln = lane & 15;
    const int n = blockIdx.x * 16 + wave * 4 + q;
    if (n >= N) return;
    const uint4* hp = (const uint4*)h16;   // 16 uint4 per row
    const int p0 = row_ptr[n], p1 = row_ptr[n + 1];
    float aA[8] = {0,0,0,0,0,0,0,0}, aB[8] = {0,0,0,0,0,0,0,0};
    float aC[8] = {0,0,0,0,0,0,0,0}, aD[8] = {0,0,0,0,0,0,0,0};
    int p = p0;
    for (; p + 3 < p1; p += 4) {
        const int s0 = csr_src[p], s1 = csr_src[p + 1], s2 = csr_src[p + 2], s3 = csr_src[p + 3];
        const f16x8 v0 = __builtin_bit_cast(f16x8, hp[(size_t)s0 * 16 + ln]);
        const f16x8 v1 = __builtin_bit_cast(f16x8, hp[(size_t)s1 * 16 + ln]);
        const f16x8 v2 = __builtin_bit_cast(f16x8, hp[(size_t)s2 * 16 + ln]);
        const f16x8 v3 = __builtin_bit_cast(f16x8, hp[(size_t)s3 * 16 + ln]);
#pragma unroll
        for (int j = 0; j < 8; ++j) {
            aA[j] += (float)v0[j]; aB[j] += (float)v1[j];
            aC[j] += (float)v2[j]; aD[j] += (float)v3[j];
        }
    }
    for (; p < p1; ++p) {
        const f16x8 v = __builtin_bit_cast(f16x8, hp[(size_t)csr_src[p] * 16 + ln]);
#pragma unroll
        for (int j = 0; j < 8; ++j) aA[j] += (float)v[j];
    }
    f16x8 r;
#pragma unroll
    for (int j = 0; j < 8; ++j) r[j] = (_Float16)((aA[j] + aB[j]) + (aC[j] + aD[j]));
    ((uint4*)S_h)[(size_t)n * 16 + ln] = __builtin_bit_cast(uint4, r);
}

// ---------------- agg kernel (512 thr, 8 waves, 256 rows/block) ----------------
__global__ __launch_bounds__(512, 2) void agg_k(
    const _Float16* __restrict__ h16,
    const _Float16* __restrict__ S_h,
    const _Float16* __restrict__ S_e,
    const int* __restrict__ row_ptr,
    const float* __restrict__ cvec,
    const _Float16* __restrict__ UWp,   // [128][320] fp16, this round's slice
    _Float16* __restrict__ agg,
    int N) {
    __shared__ __align__(16) _Float16 pbuf[2][16 * PA_STRIDE];  // 2 x 10.5 KB

    const int tid  = threadIdx.x;
    const int wave = tid >> 6;
    const int lane = tid & 63;
    const int l15  = lane & 15;
    const int lg   = lane >> 4;
    const int rbase = blockIdx.x * ROWS_BLK + wave * 32;

    const unsigned short* hp  = (const unsigned short*)h16;
    const unsigned short* shp = (const unsigned short*)S_h;
    const unsigned short* sep = (const unsigned short*)S_e;
    const unsigned short* uwp = (const unsigned short*)UWp;

    f16x8 a_h[2][4], a_sh[2][4], a_se[2][2];
#pragma unroll
    for (int m = 0; m < 2; ++m) {
        const int arow = min(rbase + m * 16 + l15, N - 1);
#pragma unroll
        for (int kb = 0; kb < 4; ++kb) {
            a_h[m][kb]  = as_f16x8(*(const u16x8*)(hp  + (size_t)arow * D_NODE + kb * 32 + lg * 8));
            a_sh[m][kb] = as_f16x8(*(const u16x8*)(shp + (size_t)arow * D_NODE + kb * 32 + lg * 8));
        }
#pragma unroll
        for (int kb = 0; kb < 2; ++kb)
            a_se[m][kb] = as_f16x8(*(const u16x8*)(sep + (size_t)arow * D_EDGE + kb * 32 + lg * 8));
    }
    float degv[2][4];
#pragma unroll
    for (int m = 0; m < 2; ++m)
#pragma unroll
        for (int i = 0; i < 4; ++i) {
            const int n = min(rbase + m * 16 + lg * 4 + i, N - 1);
            degv[m][i] = (float)(row_ptr[n + 1] - row_ptr[n]);
        }

    // panel staging: 640 16B-chunks; 512 threads -> chunk tid (all) + 512+tid (tid<128)
    u16x8 pr0, pr1;
    auto load_panel = [&](int nb) {
        const int c0 = tid, c1 = 512 + tid;
        pr0 = *(const u16x8*)(uwp + (size_t)(nb * 16 + c0 / 40) * 320 + (c0 % 40) * 8);
        if (c1 < 640)
            pr1 = *(const u16x8*)(uwp + (size_t)(nb * 16 + c1 / 40) * 320 + (c1 % 40) * 8);
    };
    auto write_panel = [&](int b) {
        const int c0 = tid, c1 = 512 + tid;
        *(u16x8*)&pbuf[b][(c0 / 40) * PA_STRIDE + (c0 % 40) * 8] = pr0;
        if (c1 < 640)
            *(u16x8*)&pbuf[b][(c1 / 40) * PA_STRIDE + (c1 % 40) * 8] = pr1;
    };

    load_panel(0);
    write_panel(0);
    __syncthreads();

#pragma unroll 1
    for (int nb = 0; nb < 8; ++nb) {
        if (nb < 7) load_panel(nb + 1);
        const _Float16* bp = pbuf[nb & 1];
        f32x4 acc1[2] = {{0.f,0.f,0.f,0.f},{0.f,0.f,0.f,0.f}};
        f32x4 acc2[2] = {{0.f,0.f,0.f,0.f},{0.f,0.f,0.f,0.f}};
#pragma unroll
        for (int kb = 0; kb < 10; ++kb) {
            f16x8 b = as_f16x8(*(const u16x8*)&bp[l15 * PA_STRIDE + kb * 32 + lg * 8]);
            if (kb < 4) {
                acc1[0] = __builtin_amdgcn_mfma_f32_16x16x32_f16(a_h[0][kb], b, acc1[0], 0, 0, 0);
                acc1[1] = __builtin_amdgcn_mfma_f32_16x16x32_f16(a_h[1][kb], b, acc1[1], 0, 0, 0);
            } else if (kb < 8) {
                acc2[0] = __builtin_amdgcn_mfma_f32_16x16x32_f16(a_sh[0][kb-4], b, acc2[0], 0, 0, 0);
                acc2[1] = __builtin_amdgcn_mfma_f32_16x16x32_f16(a_sh[1][kb-4], b, acc2[1], 0, 0, 0);
            } else {
                acc2[0] = __builtin_amdgcn_mfma_f32_16x16x32_f16(a_se[0][kb-8], b, acc2[0], 0, 0, 0);
                acc2[1] = __builtin_amdgcn_mfma_f32_16x16x32_f16(a_se[1][kb-8], b, acc2[1], 0, 0, 0);
            }
        }
        const float cv = cvec[nb * 16 + l15];
#pragma unroll
        for (int m = 0; m < 2; ++m)
#pragma unroll
            for (int i = 0; i < 4; ++i) {
                const int n = rbase + m * 16 + lg * 4 + i;
                if (n < N)
                    agg[(size_t)n * D_NODE + nb * 16 + l15] =
                        (_Float16)(degv[m][i] * (acc1[m][i] + cv) + acc2[m][i]);
            }
        if (nb < 7) write_panel((nb + 1) & 1);
        __syncthreads();
    }
}

// ---------------- GRU kernel body (shared via macro between plain / +fp32-out) --------
#define GRU_BODY(WRITE_OUT)                                                              \
    __shared__ __align__(16) _Float16 pbuf[2][96 * PB_STRIDE];                           \
    const int tid  = threadIdx.x;                                                        \
    const int wave = tid >> 6;                                                           \
    const int lane = tid & 63;                                                           \
    const int l15  = lane & 15;                                                          \
    const int lg   = lane >> 4;                                                          \
    const int rbase = blockIdx.x * ROWS_BLK + wave * 32;                                 \
    const unsigned short* hp  = (const unsigned short*)h16;                              \
    const unsigned short* agp = (const unsigned short*)agg;                              \
    const unsigned short* wih = (const unsigned short*)Wihh;                             \
    const unsigned short* whh = (const unsigned short*)Whhh;                             \
    f16x8 a_ag[2][4], a_h[2][4];                                                         \
    _Pragma("unroll")                                                                    \
    for (int m = 0; m < 2; ++m) {                                                        \
        const int arow = min(rbase + m * 16 + l15, N - 1);                               \
        _Pragma("unroll")                                                                \
        for (int kb = 0; kb < 4; ++kb) {                                                 \
            a_ag[m][kb] = as_f16x8(*(const u16x8*)(agp + (size_t)arow * D_NODE + kb * 32 + lg * 8)); \
            a_h[m][kb]  = as_f16x8(*(const u16x8*)(hp  + (size_t)arow * D_NODE + kb * 32 + lg * 8)); \
        }                                                                                \
    }                                                                                    \
    u16x8 pr[3];                                                                         \
    auto load_panel = [&](int nb) {                                                      \
        _Pragma("unroll")                                                                \
        for (int r = 0; r < 3; ++r) {                                                    \
            const int c = r * 512 + tid;                                                 \
            const int row = c >> 4;                                                      \
            const int off = (c & 15) * 8;                                                \
            const int gate = row >> 4;                                                   \
            const int col = nb * 16 + (row & 15) + (gate % 3) * D_NODE;                  \
            const unsigned short* mat = (gate < 3) ? wih : whh;                          \
            pr[r] = *(const u16x8*)(mat + (size_t)col * D_NODE + off);                   \
        }                                                                                \
    };                                                                                   \
    auto write_panel = [&](int b) {                                                      \
        _Pragma("unroll")                                                                \
        for (int r = 0; r < 3; ++r) {                                                    \
            const int c = r * 512 + tid;                                                 \
            const int row = c >> 4;                                                      \
            const int off = (c & 15) * 8;                                                \
            *(u16x8*)&pbuf[b][row * PB_STRIDE + off] = pr[r];                            \
        }                                                                                \
    };                                                                                   \
    load_panel(0);                                                                       \
    write_panel(0);                                                                      \
    __syncthreads();                                                                     \
    _Pragma("unroll 1")                                                                  \
    for (int nb = 0; nb < 8; ++nb) {                                                     \
        if (nb < 7) load_panel(nb + 1);                                                  \
        const int d = nb * 16 + l15;                                                     \
        float hv[2][4];                                                                  \
        _Pragma("unroll")                                                                \
        for (int m = 0; m < 2; ++m)                                                      \
            _Pragma("unroll")                                                            \
            for (int i = 0; i < 4; ++i) {                                                \
                const int n = min(rbase + m * 16 + lg * 4 + i, N - 1);                   \
                hv[m][i] = (float)h16[(size_t)n * D_NODE + d];                           \
            }                                                                            \
        const float bir = bih[d],       biz = bih[128 + d], bin = bih[256 + d];          \
        const float bhr = bhh[d],       bhz = bhh[128 + d], bhn = bhh[256 + d];          \
        const _Float16* bp = pbuf[nb & 1];                                               \
        f32x4 air[2] = {{0.f,0.f,0.f,0.f},{0.f,0.f,0.f,0.f}};                            \
        f32x4 aiz[2] = {{0.f,0.f,0.f,0.f},{0.f,0.f,0.f,0.f}};                            \
        f32x4 ain_[2] = {{0.f,0.f,0.f,0.f},{0.f,0.f,0.f,0.f}};                           \
        f32x4 ahr[2] = {{0.f,0.f,0.f,0.f},{0.f,0.f,0.f,0.f}};                            \
        f32x4 ahz[2] = {{0.f,0.f,0.f,0.f},{0.f,0.f,0.f,0.f}};                            \
        f32x4 ahn[2] = {{0.f,0.f,0.f,0.f},{0.f,0.f,0.f,0.f}};                            \
        _Pragma("unroll")                                                                \
        for (int kb = 0; kb < 4; ++kb) {                                                 \
            const int ko = kb * 32 + lg * 8;                                             \
            f16x8 b;                                                                     \
            b = as_f16x8(*(const u16x8*)&bp[(0 * 16 + l15) * PB_STRIDE + ko]);           \
            air[0] = __builtin_amdgcn_mfma_f32_16x16x32_f16(a_ag[0][kb], b, air[0], 0, 0, 0); \
            air[1] = __builtin_amdgcn_mfma_f32_16x16x32_f16(a_ag[1][kb], b, air[1], 0, 0, 0); \
            b = as_f16x8(*(const u16x8*)&bp[(1 * 16 + l15) * PB_STRIDE + ko]);           \
            aiz[0] = __builtin_amdgcn_mfma_f32_16x16x32_f16(a_ag[0][kb], b, aiz[0], 0, 0, 0); \
            aiz[1] = __builtin_amdgcn_mfma_f32_16x16x32_f16(a_ag[1][kb], b, aiz[1], 0, 0, 0); \
            b = as_f16x8(*(const u16x8*)&bp[(2 * 16 + l15) * PB_STRIDE + ko]);           \
            ain_[0] = __builtin_amdgcn_mfma_f32_16x16x32_f16(a_ag[0][kb], b, ain_[0], 0, 0, 0); \
            ain_[1] = __builtin_amdgcn_mfma_f32_16x16x32_f16(a_ag[1][kb], b, ain_[1], 0, 0, 0); \
            b = as_f16x8(*(const u16x8*)&bp[(3 * 16 + l15) * PB_STRIDE + ko]);           \
            ahr[0] = __builtin_amdgcn_mfma_f32_16x16x32_f16(a_h[0][kb], b, ahr[0], 0, 0, 0); \
            ahr[1] = __builtin_amdgcn_mfma_f32_16x16x32_f16(a_h[1][kb], b, ahr[1], 0, 0, 0); \
            b = as_f16x8(*(const u16x8*)&bp[(4 * 16 + l15) * PB_STRIDE + ko]);           \
            ahz[0] = __builtin_amdgcn_mfma_f32_16x16x32_f16(a_h[0][kb], b, ahz[0], 0, 0, 0); \
            ahz[1] = __builtin_amdgcn_mfma_f32_16x16x32_f16(a_h[1][kb], b, ahz[1], 0, 0, 0); \
            b = as_f16x8(*(const u16x8*)&bp[(5 * 16 + l15) * PB_STRIDE + ko]);           \
            ahn[0] = __builtin_amdgcn_mfma_f32_16x16x32_f16(a_h[0][kb], b, ahn[0], 0, 0, 0); \
            ahn[1] = __builtin_amdgcn_mfma_f32_16x16x32_f16(a_h[1][kb], b, ahn[1], 0, 0, 0); \
        }                                                                                \
        _Pragma("unroll")                                                                \
        for (int m = 0; m < 2; ++m)                                                      \
            _Pragma("unroll")                                                            \
            for (int i = 0; i < 4; ++i) {                                                \
                const int n = rbase + m * 16 + lg * 4 + i;                               \
                if (n < N) {                                                             \
                    const float r  = sigm_(air[m][i] + bir + ahr[m][i] + bhr);           \
                    const float z  = sigm_(aiz[m][i] + biz + ahz[m][i] + bhz);           \
                    const float nn = tanh_(ain_[m][i] + bin + r * (ahn[m][i] + bhn));    \
                    const float hval = (1.f - z) * nn + z * hv[m][i];                    \
                    if (WRITE_OUT) hout[(size_t)n * D_NODE + d] = hval;                  \
                    h16[(size_t)n * D_NODE + d] = (_Float16)hval;                        \
                }                                                                        \
            }                                                                            \
        if (nb < 7) write_panel((nb + 1) & 1);                                           \
        __syncthreads();                                                                 \
    }

// Rounds 0/1: fp16-state only (proven VGPR=112 codegen).
__global__ __launch_bounds__(512, 2) void gru_k(
    _Float16* __restrict__ h16,
    const _Float16* __restrict__ agg,
    const _Float16* __restrict__ Wihh,
    const _Float16* __restrict__ Whhh,
    const float* __restrict__ bih,
    const float* __restrict__ bhh,
    int N) {
    float* hout = nullptr; (void)hout;
    GRU_BODY(false)
}

// Final round: also writes fp32 output (replaces cvt_out stream kernel).
__global__ __launch_bounds__(512, 2) void gru_out_k(
    _Float16* __restrict__ h16,
    const _Float16* __restrict__ agg,
    const _Float16* __restrict__ Wihh,
    const _Float16* __restrict__ Whhh,
    const float* __restrict__ bih,
    const float* __restrict__ bhh,
    float* __restrict__ hout,
    int N) {
    GRU_BODY(true)
}

// ---------------- launch ----------------
extern "C" void kernel_launch(void* const* d_in, const int* in_sizes, int n_in,
                              void* d_out, int out_size, void* d_ws, size_t ws_size,
                              hipStream_t stream) {
    const float* h0   = (const float*)d_in[0];
    const float* e    = (const float*)d_in[1];
    const int*   src  = (const int*)d_in[2];
    const int*   dst  = (const int*)d_in[3];
    const float* cond = (const float*)d_in[4];
    const float* UW   = (const float*)d_in[5];
    const float* Ub   = (const float*)d_in[6];
    const float* Wih  = (const float*)d_in[7];
    const float* Whh  = (const float*)d_in[8];
    const float* bih  = (const float*)d_in[9];
    const float* bhh  = (const float*)d_in[10];

    const int N = in_sizes[0] / D_NODE;
    const int E = in_sizes[2];
    const int NB = (N + 1023) / 1024;   // scan blocks (<= 256)
    const int NT = (N + ROWS_BLK - 1) / ROWS_BLK;

    char* wsb = (char*)d_ws;
    size_t off = 0;
    auto carve = [&](size_t bytes) -> char* {
        char* p = wsb + off;
        off = (off + bytes + 255) & ~(size_t)255;
        return p;
    };
    int*   cnt      = (int*)carve((size_t)N * 4);
    int*   row_ptr  = (int*)carve(((size_t)N + 1) * 4);
    int*   cursor   = (int*)carve((size_t)N * 4);
    int*   csr_src  = (int*)carve((size_t)E * 4);
    int*   csr_eid  = (int*)carve((size_t)E * 4);
    int*   blk_sums = (int*)carve(256 * 4);
    float* cvec     = (float*)carve(3 * D_NODE * 4);
    _Float16* S_e  = (_Float16*)carve((size_t)N * D_EDGE * 2);
    _Float16* S_h  = (_Float16*)carve((size_t)N * D_NODE * 2);
    _Float16* aggb = (_Float16*)carve((size_t)N * D_NODE * 2);
    _Float16* h16  = (_Float16*)carve((size_t)N * D_NODE * 2);
    _Float16* UWp  = (_Float16*)carve((size_t)3 * D_NODE * 320 * 2);
    _Float16* Wihh = (_Float16*)carve((size_t)3 * GRU3 * D_NODE * 2);
    _Float16* Whhh = (_Float16*)carve((size_t)3 * GRU3 * D_NODE * 2);
    const size_t e16_bytes = (size_t)E * D_EDGE * 2;
    _Float16* e16 = nullptr;
    if (off + e16_bytes + 256 <= ws_size) e16 = (_Float16*)carve(e16_bytes);
    (void)n_in; (void)out_size;

    hipMemsetAsync(cnt, 0, (size_t)N * 4, stream);
    hist_k<<<(E + 255) / 256, 256, 0, stream>>>(dst, cnt, E);
    scan1_k<<<NB, 256, 0, stream>>>(cnt, row_ptr, blk_sums, N);
    scan2_k<<<1, 256, 0, stream>>>(blk_sums, NB, row_ptr, N, E);
    scan3_k<<<NB, 256, 0, stream>>>(row_ptr, cursor, blk_sums, N);
    scatter_k<<<(E + 255) / 256, 256, 0, stream>>>(src, dst, cursor, csr_src, csr_eid, E);
    compute_c_k<<<1, 384, 0, stream>>>(UW, Ub, cond, cvec);
    cvt_uwp_k<<<3 * D_NODE, 320, 0, stream>>>(UW, UWp);
    {
        const int n1 = 3 * GRU3 * D_NODE;
        cvt_f32_k<<<(n1 + 255) / 256, 256, 0, stream>>>(Wih, Wihh, n1);
        cvt_f32_k<<<(n1 + 255) / 256, 256, 0, stream>>>(Whh, Whhh, n1);
    }
    {
        const int n4 = N * D_NODE / 4;
        cvt4_k<<<(n4 + 255) / 256, 256, 0, stream>>>(h0, h16, n4);   // seed fp16 mirror
    }
    if (e16) {
        const int n4 = E * D_EDGE / 4;
        cvt4_k<<<(n4 + 255) / 256, 256, 0, stream>>>(e, e16, n4);
        gather_e16_k<<<(N + 15) / 16, 256, 0, stream>>>(e16, row_ptr, csr_eid, S_e, N);
    } else {
        gather_e_k<<<(N + 3) / 4, 256, 0, stream>>>(e, row_ptr, csr_eid, S_e, N);
    }

    for (int k = 0; k < 3; ++k) {
        gather_h_k<<<(N + 15) / 16, 256, 0, stream>>>(h16, row_ptr, csr_src, S_h, N);
        agg_k<<<NT, 512, 0, stream>>>(
            h16, S_h, S_e, row_ptr, cvec + k * D_NODE,
            UWp + (size_t)k * D_NODE * 320, aggb, N);
        if (k < 2) {
            gru_k<<<NT, 512, 0, stream>>>(
                h16, aggb,
                Wihh + (size_t)k * GRU3 * D_NODE,
                Whhh + (size_t)k * GRU3 * D_NODE,
                bih + (size_t)k * GRU3,
                bhh + (size_t)k * GRU3,
                N);
        } else {
            gru_out_k<<<NT, 512, 0, stream>>>(
                h16, aggb,
                Wihh + (size_t)k * GRU3 * D_NODE,
                Whhh + (size_t)k * GRU3 * D_NODE,
                bih + (size_t)k * GRU3,
                bhh + (size_t)k * GRU3,
                (float*)d_out, N);
        }
    }
}